// Round 1
// baseline (1781.434 us; speedup 1.0000x reference)
//
#include <hip/hip_runtime.h>
#include <math.h>

#define PI_D 3.14159265358979323846

// ---- static problem sizes (from reference) ----
#define BATCH 128
#define F1 20
#define F2 40
#define FOUT 10
#define NS1 100   // sum_{l<10} (2l+1)
#define NS2 286   // sum_{l<6} (2l+1)^2

// cumulative (2l+1)^2 offsets, l=0..9 (stage-1 z / D1S) and l=0..5 (stage-2)
__constant__ int ZB10c[11] = {0,1,10,35,84,165,286,455,680,969,1330};
__constant__ int B2OFFc[7] = {0,1,10,35,84,165,286};

// ---------------- double-precision table generation helpers ----------------
__device__ inline double ipow_d(double x, int n){ double r=1.0; for(int i=0;i<n;++i) r*=x; return r; }
__device__ inline double dfact(int n){ double r=1.0; for(int i=2;i<=n;++i) r*=(double)i; return r; }

__device__ double wigd(int l, int mp, int m, double beta){
  double cb=cos(0.5*beta), sb=sin(0.5*beta);
  double pref=sqrt(dfact(l+mp)*dfact(l-mp)*dfact(l+m)*dfact(l-m));
  int s0 = (m-mp>0) ? (m-mp) : 0;
  int s1 = (l+m < l-mp) ? (l+m) : (l-mp);
  double acc=0.0;
  for(int s=s0;s<=s1;++s){
    double den=dfact(l+m-s)*dfact(s)*dfact(mp-m+s)*dfact(l-mp-s);
    double t=ipow_d(cb,2*l+m-mp-2*s)*ipow_d(sb,mp-m+2*s)/den;
    acc += ((mp-m+s)&1)? -t : t;
  }
  return pref*acc;
}

__device__ double dhw(int b, int j){   // Driscoll-Healy weight
  double beta=PI_D*(2*j+1)/(4.0*b);
  double s=0.0;
  for(int k=0;k<b;++k) s += sin((2*k+1)*beta)/(2*k+1);
  return (2.0/b)*sin(beta)*s;
}

__device__ inline float2 cmulc(float2 a, float2 b){ // a * conj(b)
  return make_float2(a.x*b.x + a.y*b.y, a.y*b.x - a.x*b.y);
}

// ---------------- table generation kernels ----------------
__global__ void gen_A1(float* A1){
  int idx=blockIdx.x*blockDim.x+threadIdx.x; if(idx>=60*NS1) return;
  int j=idx/NS1, s=idx%NS1;
  int l=0; while((l+1)*(l+1)<=s) ++l;
  int m=s-l*l-l;
  double beta=PI_D*(2*j+1)/120.0;
  A1[idx]=(float)(wigd(l,m,0,beta)*dhw(30,j)*(2.0*PI_D/60.0));
}

__global__ void gen_Y1(float2* Y1){
  int idx=blockIdx.x*blockDim.x+threadIdx.x; if(idx>=24*NS1) return;
  int p=idx/NS1, s=idx%NS1;
  int l=0; while((l+1)*(l+1)<=s) ++l;
  int m=s-l*l-l;
  int bi=p/8, ai=p%8;
  double beta=(bi+1)*(PI_D/8.0)/3.0;
  double alpha=2.0*PI_D*ai/8.0;
  double d=wigd(l,m,0,beta);
  double ph=-alpha*m;
  Y1[idx]=make_float2((float)(d*cos(ph)),(float)(d*sin(ph)));
}

__global__ void gen_D1S(float* D1S){
  int idx=blockIdx.x*blockDim.x+threadIdx.x; if(idx>=26600) return;
  int l=0; while(20*ZB10c[l+1]<=idx) ++l;
  int rem=idx-20*ZB10c[l]; int L=2*l+1, LL=L*L;
  int j=rem/LL, r2=rem%LL, mi=r2/L, ni=r2%L;
  double beta=PI_D*(2*j+1)/40.0;
  D1S[idx]=(float)((2*l+1)*wigd(l,mi-l,ni-l,beta));
}

__global__ void gen_W3(float* W3){
  int idx=blockIdx.x*blockDim.x+threadIdx.x; if(idx>=20*NS2) return;
  int j=idx/NS2, s=idx%NS2;
  int l=0; while(B2OFFc[l+1]<=s) ++l;
  int r=s-B2OFFc[l]; int L=2*l+1;
  int m=r/L-l, n=r%L-l;
  double beta=PI_D*(2*j+1)/40.0;
  double c=2.0*PI_D/20.0;
  W3[idx]=(float)(wigd(l,m,n,beta)*dhw(10,j)*c*c);
}

__global__ void gen_Y2(float2* Y2){
  int idx=blockIdx.x*blockDim.x+threadIdx.x; if(idx>=192*NS2) return;
  int p=idx/NS2, s=idx%NS2;
  int l=0; while(B2OFFc[l+1]<=s) ++l;
  int r=s-B2OFFc[l]; int L=2*l+1;
  int m=r/L-l, n=r%L-l;
  int bi=p/64, ai=(p/8)%8, gi=p%8;
  double beta=(bi+1)*(PI_D/8.0)/3.0;
  double alpha=2.0*PI_D*ai/8.0;
  double gamma=2.0*PI_D*gi/8.0 - alpha;
  double d=wigd(l,m,n,beta);
  double ph=-(alpha*m+gamma*n);
  Y2[idx]=make_float2((float)(d*cos(ph)),(float)(d*sin(ph)));
}

__global__ void gen_D2S(float* D2S){
  int idx=blockIdx.x*blockDim.x+threadIdx.x; if(idx>=3432) return;
  int l=0; while(12*B2OFFc[l+1]<=idx) ++l;
  int rem=idx-12*B2OFFc[l]; int L=2*l+1, LL=L*L;
  int j=rem/LL, r2=rem%LL, mi=r2/L, ni=r2%L;
  double beta=PI_D*(2*j+1)/24.0;
  D2S[idx]=(float)((2*l+1)*wigd(l,mi-l,ni-l,beta));
}

__global__ void gen_misc(float* WINT, float2* E60, float2* E20, float2* E12){
  int t=threadIdx.x;
  if(t<12){ double c=2.0*PI_D/12.0; WINT[t]=(float)(dhw(6,t)*c*c); }
  if(t<60){ double a=2.0*PI_D*t/60.0; E60[t]=make_float2((float)cos(a),(float)sin(a)); }
  if(t<20){ double a=2.0*PI_D*t/20.0; E20[t]=make_float2((float)cos(a),(float)sin(a)); }
  if(t<12){ double a=2.0*PI_D*t/12.0; E12[t]=make_float2((float)cos(a),(float)sin(a)); }
}

// ---------------- stage kernels ----------------
// DFT of x over alpha at the 19 needed frequencies m=-9..9
__global__ void dft60_k(const float* __restrict__ x, const float2* __restrict__ E60,
                        float2* __restrict__ XF){
  int idx=blockIdx.x*blockDim.x+threadIdx.x;
  if(idx>=BATCH*60*19) return;
  int mi=idx%19, r=idx/19;
  int j=r%60, b=r/60;
  int m=mi-9;
  const float* xr = x + b*3600 + j*60;
  float2 acc=make_float2(0.f,0.f);
  for(int a=0;a<60;++a){
    int k=((m*a)%60+60)%60;
    float2 e=E60[k];
    float xv=xr[a];
    acc.x += xv*e.x;
    acc.y -= xv*e.y;
  }
  XF[idx]=acc;
}

// S2 spectrum: xhat[s][b] = sum_j A1[j,s] * XF[b,j,m_s]
__global__ void xhat_k(const float2* __restrict__ XF, const float* __restrict__ A1,
                       float2* __restrict__ XHAT){
  int idx=blockIdx.x*blockDim.x+threadIdx.x;
  if(idx>=NS1*BATCH) return;
  int b=idx%BATCH, s=idx/BATCH;
  int l=0; while((l+1)*(l+1)<=s) ++l;
  int m=s-l*l-l;
  float2 acc=make_float2(0.f,0.f);
  for(int j=0;j<60;++j){
    float a1=A1[j*NS1+s];
    float2 xf=XF[(b*60+j)*19 + (m+9)];
    acc.x += a1*xf.x; acc.y += a1*xf.y;
  }
  XHAT[s*BATCH+b]=acc;
}

__global__ void k1h_k(const float* __restrict__ k1, const float2* __restrict__ Y1,
                      float2* __restrict__ K1H){
  int idx=blockIdx.x*blockDim.x+threadIdx.x;
  if(idx>=NS1*F1) return;
  int o=idx%F1, s=idx/F1;
  float2 acc=make_float2(0.f,0.f);
  for(int p=0;p<24;++p){
    float kv=k1[o*24+p];
    float2 y=Y1[p*NS1+s];
    acc.x+=kv*y.x; acc.y+=kv*y.y;
  }
  const float SC1f = 0.06123724356957945f; // 1/sqrt(24*10^4/30^2)
  K1H[s*F1+o]=make_float2(acc.x*SC1f, acc.y*SC1f);
}

// fused: conv1 SO3 synthesis (per beta row) + bias/relu + conv2 SO3 analysis
__global__ __launch_bounds__(256) void fused1(
    const float2* __restrict__ XHAT, const float2* __restrict__ K1H,
    const float* __restrict__ D1S, const float* __restrict__ W3,
    const float2* __restrict__ E20, const float* __restrict__ bias1,
    float2* __restrict__ XH2){
  const int b=blockIdx.x, o=blockIdx.y, t=threadIdx.x;
  __shared__ float2 z[1330];
  __shared__ float2 G[361];     // 19x19 freq block, m,n=-9..9
  __shared__ float2 T[380];     // 19 m x 20 g
  __shared__ float  v[400];     // 20 a x 20 g spatial tile
  __shared__ float2 U[220];     // 20 a x 11 nu
  __shared__ float2 Fq[121];    // 11 mu x 11 nu
  __shared__ float2 acc2[286];
  for(int idx=t; idx<1330; idx+=256){
    int l=0; while(ZB10c[l+1]<=idx) ++l;
    int r=idx-ZB10c[l], L=2*l+1;
    int mi=r/L, ni=r%L;
    float2 xa=XHAT[(l*l+mi)*BATCH+b];
    float2 kb=K1H[(l*l+ni)*F1+o];
    z[idx]=cmulc(xa,kb);
  }
  for(int idx=t; idx<286; idx+=256) acc2[idx]=make_float2(0.f,0.f);
  __syncthreads();
  const float bb1=bias1[o];
  for(int j=0;j<20;++j){
    for(int idx=t; idx<361; idx+=256){
      int m=idx/19-9, n=idx%19-9;
      int am=m<0?-m:m, an=n<0?-n:n;
      int lmin=am>an?am:an;
      float2 acc=make_float2(0.f,0.f);
      for(int l=lmin;l<10;++l){
        int L=2*l+1;
        float2 zv=z[ZB10c[l]+(m+l)*L+(n+l)];
        float dv=D1S[20*ZB10c[l]+j*L*L+(m+l)*L+(n+l)];
        acc.x += zv.x*dv; acc.y += zv.y*dv;
      }
      G[idx]=acc;
    }
    __syncthreads();
    for(int idx=t; idx<380; idx+=256){
      int mi=idx/20, g=idx%20;
      float2 acc=make_float2(0.f,0.f);
      for(int ni=0; ni<19; ++ni){
        int k=(((ni-9)*g)%20+20)%20;
        float2 e=E20[k];
        float2 gv=G[mi*19+ni];
        acc.x += gv.x*e.x - gv.y*e.y;
        acc.y += gv.x*e.y + gv.y*e.x;
      }
      T[idx]=acc;
    }
    __syncthreads();
    for(int idx=t; idx<400; idx+=256){
      int a=idx/20, g=idx%20;
      float val=0.f;
      for(int mi=0; mi<19; ++mi){
        int k=(((mi-9)*a)%20+20)%20;
        float2 e=E20[k];
        float2 tv=T[mi*20+g];
        val += tv.x*e.x - tv.y*e.y;  // real part of synthesis
      }
      val += bb1;
      v[idx]=val>0.f?val:0.f;
    }
    __syncthreads();
    for(int idx=t; idx<220; idx+=256){
      int a=idx/11, ni=idx%11;
      int nu=ni-5;
      float2 acc=make_float2(0.f,0.f);
      for(int g=0; g<20; ++g){
        int k=((nu*g)%20+20)%20;
        float2 e=E20[k];
        float vv=v[a*20+g];
        acc.x += vv*e.x;
        acc.y -= vv*e.y;   // v * conj(e)
      }
      U[idx]=acc;
    }
    __syncthreads();
    for(int idx=t; idx<121; idx+=256){
      int mi=idx/11, ni=idx%11;
      int mu=mi-5;
      float2 acc=make_float2(0.f,0.f);
      for(int a=0;a<20;++a){
        int k=((mu*a)%20+20)%20;
        float2 e=E20[k];
        float2 uv=U[a*11+ni];
        acc.x += uv.x*e.x + uv.y*e.y;  // U * conj(e)
        acc.y += uv.y*e.x - uv.x*e.y;
      }
      Fq[idx]=acc;
    }
    __syncthreads();
    for(int idx=t; idx<286; idx+=256){
      int l=0; while(B2OFFc[l+1]<=idx) ++l;
      int r=idx-B2OFFc[l], L=2*l+1;
      int m=r/L-l, n=r%L-l;
      float w=W3[j*286+idx];
      float2 f=Fq[(m+5)*11+(n+5)];
      acc2[idx].x += w*f.x;
      acc2[idx].y += w*f.y;
    }
    __syncthreads();
  }
  for(int idx=t; idx<286; idx+=256){
    XH2[idx*(BATCH*F1) + b*F1 + o] = acc2[idx];
  }
}

__global__ void k2h_k(const float* __restrict__ k2, const float2* __restrict__ Y2,
                      float2* __restrict__ K2H){
  int idx=blockIdx.x*blockDim.x+threadIdx.x;
  if(idx>=NS2*F1*F2) return;
  int s=idx/(F1*F2); int r=idx%(F1*F2); int i=r/F2, o=r%F2;
  float2 acc=make_float2(0.f,0.f);
  const float* kr=k2+(i*F2+o)*192;
  for(int p=0;p<192;++p){
    float kv=kr[p];
    float2 y=Y2[p*NS2+s];
    acc.x+=kv*y.x; acc.y+=kv*y.y;
  }
  const float SC2f = 0.034722222222222224f; // 1/sqrt(192*20*216/1000) = 1/28.8
  K2H[s*(F1*F2)+i*F2+o]=make_float2(acc.x*SC2f, acc.y*SC2f);
}

// fused: conv2 z build + SO3 synthesis + bias/relu + so3_integrate
__global__ __launch_bounds__(256) void fused2(
    const float2* __restrict__ XH2, const float2* __restrict__ K2H,
    const float* __restrict__ D2S, const float* __restrict__ WINT,
    const float2* __restrict__ E12, const float* __restrict__ bias2,
    float* __restrict__ FEAT){
  const int b=blockIdx.x, o=blockIdx.y, t=threadIdx.x;
  __shared__ float2 z2[286];
  __shared__ float2 G2[121];
  __shared__ float2 T2[132];
  __shared__ float red[256];
  for(int idx=t; idx<286; idx+=256){
    int l=0; while(B2OFFc[l+1]<=idx) ++l;
    int r=idx-B2OFFc[l], L=2*l+1;
    int mi=r/L, ni=r%L;
    float2 acc=make_float2(0.f,0.f);
    for(int k=0;k<L;++k){
      const float2* xr = XH2 + (B2OFFc[l]+mi*L+k)*(BATCH*F1) + b*F1;
      const float2* kr = K2H + (B2OFFc[l]+ni*L+k)*(F1*F2) + o;
      for(int i=0;i<F1;++i){
        float2 xa=xr[i];
        float2 kb=kr[i*F2];
        acc.x += xa.x*kb.x + xa.y*kb.y;  // xa * conj(kb)
        acc.y += xa.y*kb.x - xa.x*kb.y;
      }
    }
    z2[idx]=acc;
  }
  __syncthreads();
  float personal=0.f;
  const float b2=bias2[o];
  const int a=t/12, g=t%12;   // valid for t<144
  for(int j=0;j<12;++j){
    for(int idx=t; idx<121; idx+=256){
      int m=idx/11-5, n=idx%11-5;
      int am=m<0?-m:m, an=n<0?-n:n;
      int lmin=am>an?am:an;
      float2 acc=make_float2(0.f,0.f);
      for(int l=lmin;l<6;++l){
        int L=2*l+1;
        float2 zv=z2[B2OFFc[l]+(m+l)*L+(n+l)];
        float dv=D2S[12*B2OFFc[l]+j*L*L+(m+l)*L+(n+l)];
        acc.x += zv.x*dv; acc.y += zv.y*dv;
      }
      G2[idx]=acc;
    }
    __syncthreads();
    for(int idx=t; idx<132; idx+=256){
      int mi=idx/12, gg=idx%12;
      float2 acc=make_float2(0.f,0.f);
      for(int ni=0; ni<11; ++ni){
        int k=(((ni-5)*gg)%12+12)%12;
        float2 e=E12[k];
        float2 gv=G2[mi*11+ni];
        acc.x += gv.x*e.x - gv.y*e.y;
        acc.y += gv.x*e.y + gv.y*e.x;
      }
      T2[idx]=acc;
    }
    __syncthreads();
    if(t<144){
      float val=0.f;
      for(int mi=0; mi<11; ++mi){
        int k=(((mi-5)*a)%12+12)%12;
        float2 e=E12[k];
        float2 tv=T2[mi*12+g];
        val += tv.x*e.x - tv.y*e.y;
      }
      val += b2;
      if(val>0.f) personal += WINT[j]*val;
    }
    __syncthreads();
  }
  red[t]=(t<144)? personal : 0.f;
  __syncthreads();
  for(int sft=128; sft>0; sft>>=1){
    if(t<sft) red[t]+=red[t+sft];
    __syncthreads();
  }
  if(t==0) FEAT[b*F2+o]=red[0];
}

__global__ void head_k(const float* __restrict__ FEAT, const float* __restrict__ w_out,
                       const float* __restrict__ b_lin, float* __restrict__ out){
  int idx=blockIdx.x*blockDim.x+threadIdx.x;
  if(idx>=BATCH*FOUT) return;
  int b=idx/FOUT, q=idx%FOUT;
  float acc=b_lin[q];
  for(int f=0;f<F2;++f) acc += FEAT[b*F2+f]*w_out[q*F2+f];
  out[idx]=acc;
}

extern "C" void kernel_launch(void* const* d_in, const int* in_sizes, int n_in,
                              void* d_out, int out_size, void* d_ws, size_t ws_size,
                              hipStream_t stream) {
  const float* x    =(const float*)d_in[0];
  const float* k1   =(const float*)d_in[1];
  const float* bias1=(const float*)d_in[2];
  const float* k2   =(const float*)d_in[3];
  const float* bias2=(const float*)d_in[4];
  const float* w_out=(const float*)d_in[5];
  const float* b_lin=(const float*)d_in[6];
  float* out=(float*)d_out;

  // ---- ws layout (bytes), total ~9.62 MB ----
  char* ws=(char*)d_ws;
  float*  A1  =(float* )(ws+0);        //  60*100 f        24000
  float2* Y1  =(float2*)(ws+24000);    //  24*100 c        19200
  float*  D1S =(float* )(ws+43200);    //  26600 f         106400
  float*  W3  =(float* )(ws+149600);   //  20*286 f        22880
  float2* Y2  =(float2*)(ws+172480);   //  192*286 c       439296
  float*  D2S =(float* )(ws+611776);   //  3432 f          13728
  float*  WINT=(float* )(ws+625504);   //  12 f            48
  float2* E60 =(float2*)(ws+625552);   //  60 c            480
  float2* E20 =(float2*)(ws+626032);   //  20 c            160
  float2* E12 =(float2*)(ws+626192);   //  12 c            96 (+pad)
  float2* XF  =(float2*)(ws+626304);   //  128*60*19 c     1167360
  float2* XHAT=(float2*)(ws+1793664);  //  100*128 c       102400
  float2* K1H =(float2*)(ws+1896064);  //  100*20 c        16000
  float2* XH2 =(float2*)(ws+1912064);  //  286*128*20 c    5857280
  float2* K2H =(float2*)(ws+7769344);  //  286*20*40 c     1830400
  float*  FEAT=(float* )(ws+9599744);  //  128*40 f        20480  -> 9620224 total

  (void)in_sizes; (void)n_in; (void)out_size; (void)ws_size;

  // table generation (deterministic, double precision, on device)
  gen_A1 <<<(60*NS1+255)/256,256,0,stream>>>(A1);
  gen_Y1 <<<(24*NS1+255)/256,256,0,stream>>>(Y1);
  gen_D1S<<<(26600+255)/256,256,0,stream>>>(D1S);
  gen_W3 <<<(20*NS2+255)/256,256,0,stream>>>(W3);
  gen_Y2 <<<(192*NS2+255)/256,256,0,stream>>>(Y2);
  gen_D2S<<<(3432+255)/256,256,0,stream>>>(D2S);
  gen_misc<<<1,64,0,stream>>>(WINT,E60,E20,E12);

  // pipeline
  dft60_k<<<(BATCH*60*19+255)/256,256,0,stream>>>(x,E60,XF);
  xhat_k <<<(NS1*BATCH+255)/256,256,0,stream>>>(XF,A1,XHAT);
  k1h_k  <<<(NS1*F1+255)/256,256,0,stream>>>(k1,Y1,K1H);
  dim3 g1(BATCH,F1);
  fused1 <<<g1,256,0,stream>>>(XHAT,K1H,D1S,W3,E20,bias1,XH2);
  k2h_k  <<<(NS2*F1*F2+255)/256,256,0,stream>>>(k2,Y2,K2H);
  dim3 g2(BATCH,F2);
  fused2 <<<g2,256,0,stream>>>(XH2,K2H,D2S,WINT,E12,bias2,FEAT);
  head_k <<<(BATCH*FOUT+255)/256,256,0,stream>>>(FEAT,w_out,b_lin,out);
}

// Round 2
// 634.529 us; speedup vs baseline: 2.8075x; 2.8075x over previous
//
#include <hip/hip_runtime.h>
#include <math.h>

#define PI_D 3.14159265358979323846

#define BATCH 128
#define F1 20
#define F2 40
#define FOUT 10
#define NS1 100   // sum_{l<10} (2l+1)
#define NS2 286   // sum_{l<6} (2l+1)^2

__constant__ int ZB10c[11] = {0,1,10,35,84,165,286,455,680,969,1330};
__constant__ int B2OFFc[7] = {0,1,10,35,84,165,286};

// ---------------- double-precision table generation helpers ----------------
__device__ inline double ipow_d(double x, int n){ double r=1.0; for(int i=0;i<n;++i) r*=x; return r; }
__device__ inline double dfact(int n){ double r=1.0; for(int i=2;i<=n;++i) r*=(double)i; return r; }

__device__ double wigd(int l, int mp, int m, double beta){
  double cb=cos(0.5*beta), sb=sin(0.5*beta);
  double pref=sqrt(dfact(l+mp)*dfact(l-mp)*dfact(l+m)*dfact(l-m));
  int s0 = (m-mp>0) ? (m-mp) : 0;
  int s1 = (l+m < l-mp) ? (l+m) : (l-mp);
  double acc=0.0;
  for(int s=s0;s<=s1;++s){
    double den=dfact(l+m-s)*dfact(s)*dfact(mp-m+s)*dfact(l-mp-s);
    double t=ipow_d(cb,2*l+m-mp-2*s)*ipow_d(sb,mp-m+2*s)/den;
    acc += ((mp-m+s)&1)? -t : t;
  }
  return pref*acc;
}

__device__ double dhw(int b, int j){
  double beta=PI_D*(2*j+1)/(4.0*b);
  double s=0.0;
  for(int k=0;k<b;++k) s += sin((2*k+1)*beta)/(2*k+1);
  return (2.0/b)*sin(beta)*s;
}

__device__ inline float2 cmulc(float2 a, float2 b){ // a * conj(b)
  return make_float2(a.x*b.x + a.y*b.y, a.y*b.x - a.x*b.y);
}

// ---------------- table generation kernels ----------------
__global__ void gen_A1(float* A1){
  int idx=blockIdx.x*blockDim.x+threadIdx.x; if(idx>=60*NS1) return;
  int j=idx/NS1, s=idx%NS1;
  int l=0; while((l+1)*(l+1)<=s) ++l;
  int m=s-l*l-l;
  double beta=PI_D*(2*j+1)/120.0;
  A1[idx]=(float)(wigd(l,m,0,beta)*dhw(30,j)*(2.0*PI_D/60.0));
}

__global__ void gen_Y1(float2* Y1){
  int idx=blockIdx.x*blockDim.x+threadIdx.x; if(idx>=24*NS1) return;
  int p=idx/NS1, s=idx%NS1;
  int l=0; while((l+1)*(l+1)<=s) ++l;
  int m=s-l*l-l;
  int bi=p/8, ai=p%8;
  double beta=(bi+1)*(PI_D/8.0)/3.0;
  double alpha=2.0*PI_D*ai/8.0;
  double d=wigd(l,m,0,beta);
  double ph=-alpha*m;
  Y1[idx]=make_float2((float)(d*cos(ph)),(float)(d*sin(ph)));
}

// D1SJ layout: [j][1330] with (l,mi,ni) packed at ZB10c[l]+mi*L+ni
__global__ void gen_D1S(float* D1SJ){
  int idx=blockIdx.x*blockDim.x+threadIdx.x; if(idx>=26600) return;
  int j=idx/1330, s=idx%1330;
  int l=0; while(ZB10c[l+1]<=s) ++l;
  int r=s-ZB10c[l]; int L=2*l+1;
  int mi=r/L, ni=r%L;
  double beta=PI_D*(2*j+1)/40.0;
  D1SJ[idx]=(float)((2*l+1)*wigd(l,mi-l,ni-l,beta));
}

__global__ void gen_W3(float* W3){
  int idx=blockIdx.x*blockDim.x+threadIdx.x; if(idx>=20*NS2) return;
  int j=idx/NS2, s=idx%NS2;
  int l=0; while(B2OFFc[l+1]<=s) ++l;
  int r=s-B2OFFc[l]; int L=2*l+1;
  int m=r/L-l, n=r%L-l;
  double beta=PI_D*(2*j+1)/40.0;
  double c=2.0*PI_D/20.0;
  W3[idx]=(float)(wigd(l,m,n,beta)*dhw(10,j)*c*c);
}

__global__ void gen_Y2(float2* Y2){
  int idx=blockIdx.x*blockDim.x+threadIdx.x; if(idx>=192*NS2) return;
  int p=idx/NS2, s=idx%NS2;
  int l=0; while(B2OFFc[l+1]<=s) ++l;
  int r=s-B2OFFc[l]; int L=2*l+1;
  int m=r/L-l, n=r%L-l;
  int bi=p/64, ai=(p/8)%8, gi=p%8;
  double beta=(bi+1)*(PI_D/8.0)/3.0;
  double alpha=2.0*PI_D*ai/8.0;
  double gamma=2.0*PI_D*gi/8.0 - alpha;
  double d=wigd(l,m,n,beta);
  double ph=-(alpha*m+gamma*n);
  Y2[idx]=make_float2((float)(d*cos(ph)),(float)(d*sin(ph)));
}

// D2SJ layout: [j][286]
__global__ void gen_D2S(float* D2SJ){
  int idx=blockIdx.x*blockDim.x+threadIdx.x; if(idx>=3432) return;
  int j=idx/286, s=idx%286;
  int l=0; while(B2OFFc[l+1]<=s) ++l;
  int r=s-B2OFFc[l]; int L=2*l+1;
  int mi=r/L, ni=r%L;
  double beta=PI_D*(2*j+1)/24.0;
  D2SJ[idx]=(float)((2*l+1)*wigd(l,mi-l,ni-l,beta));
}

__global__ void gen_misc(float* WINT, float2* E60, float2* E20, float2* E12){
  int t=threadIdx.x;
  if(t<12){ double c=2.0*PI_D/12.0; WINT[t]=(float)(dhw(6,t)*c*c); }
  if(t<60){ double a=2.0*PI_D*t/60.0; E60[t]=make_float2((float)cos(a),(float)sin(a)); }
  if(t<20){ double a=2.0*PI_D*t/20.0; E20[t]=make_float2((float)cos(a),(float)sin(a)); }
  if(t<12){ double a=2.0*PI_D*t/12.0; E12[t]=make_float2((float)cos(a),(float)sin(a)); }
}

// ---------------- stage kernels ----------------
__global__ __launch_bounds__(256) void dft60_k(const float* __restrict__ x,
                        const float2* __restrict__ E60, float2* __restrict__ XF){
  __shared__ float2 E60s[60];
  int t=threadIdx.x;
  if(t<60) E60s[t]=E60[t];
  __syncthreads();
  int idx=blockIdx.x*blockDim.x+t;
  if(idx>=BATCH*60*19) return;
  int mi=idx%19, r=idx/19;
  int j=r%60, b=r/60;
  int step=((mi-9)+60)%60;
  const float* xr = x + b*3600 + j*60;
  float2 acc=make_float2(0.f,0.f);
  int k=0;
  for(int a=0;a<60;++a){
    float2 e=E60s[k];
    float xv=xr[a];
    acc.x += xv*e.x;
    acc.y -= xv*e.y;
    k+=step; if(k>=60)k-=60;
  }
  XF[idx]=acc;
}

// XHAT layout: [b][s1]
__global__ void xhat_k(const float2* __restrict__ XF, const float* __restrict__ A1,
                       float2* __restrict__ XHAT){
  int idx=blockIdx.x*blockDim.x+threadIdx.x;
  if(idx>=BATCH*NS1) return;
  int b=idx/NS1, s=idx%NS1;
  int l=0; while((l+1)*(l+1)<=s) ++l;
  int m=s-l*l-l;
  const float2* xf=XF + b*60*19 + (m+9);
  float2 acc=make_float2(0.f,0.f);
  for(int j=0;j<60;++j){
    float a1=A1[j*NS1+s];
    float2 v=xf[j*19];
    acc.x += a1*v.x; acc.y += a1*v.y;
  }
  XHAT[idx]=acc;
}

// K1H layout: [o][s1]
__global__ void k1h_k(const float* __restrict__ k1, const float2* __restrict__ Y1,
                      float2* __restrict__ K1H){
  int idx=blockIdx.x*blockDim.x+threadIdx.x;
  if(idx>=F1*NS1) return;
  int o=idx/NS1, s=idx%NS1;
  float2 acc=make_float2(0.f,0.f);
  for(int p=0;p<24;++p){
    float kv=k1[o*24+p];
    float2 y=Y1[p*NS1+s];
    acc.x+=kv*y.x; acc.y+=kv*y.y;
  }
  const float SC1f = 0.06123724356957945f;
  K1H[idx]=make_float2(acc.x*SC1f, acc.y*SC1f);
}

// fused1: conv1 SO3 synthesis + relu + conv2-analysis accumulate.
// XH2 layout: [b][s2][i]  (i = F1 channel)
__global__ __launch_bounds__(256) void fused1(
    const float2* __restrict__ XHAT, const float2* __restrict__ K1H,
    const float* __restrict__ D1SJ, const float* __restrict__ W3,
    const float2* __restrict__ E20, const float* __restrict__ bias1,
    float2* __restrict__ XH2){
  const int b=blockIdx.x, o=blockIdx.y, t=threadIdx.x;
  __shared__ float2 z[1330];
  __shared__ __align__(16) float Dj[2][1330];
  __shared__ float2 GUF[722];       // G0/G1, later U0/U1/Fq0/Fq1
  __shared__ float2 T[2][380];
  __shared__ float  v[2][400];
  __shared__ float2 acc2[286];
  __shared__ float2 E20s[20];
  __shared__ int    zbS[11];
  __shared__ short  map286S[286];
  float2* G0=GUF;       float2* G1=GUF+361;
  float2* U0=GUF;       float2* U1=GUF+220;
  float2* Fq0=GUF+440;  float2* Fq1=GUF+561;

  if(t<11) zbS[t]=ZB10c[t];
  if(t<20) E20s[t]=E20[t];
  for(int idx=t; idx<286; idx+=256){
    int l=0; while(B2OFFc[l+1]<=idx) ++l;
    int r=idx-B2OFFc[l], L=2*l+1;
    int m=r/L-l, n=r%L-l;
    map286S[idx]=(short)((m+5)*11+(n+5));
  }
  for(int idx=t; idx<1330; idx+=256){
    int l=0; while(ZB10c[l+1]<=idx) ++l;
    int r=idx-ZB10c[l], L=2*l+1;
    int mi=r/L, ni=r%L;
    float2 xa=XHAT[b*NS1 + l*l+mi];
    float2 kb=K1H[o*NS1 + l*l+ni];
    z[idx]=cmulc(xa,kb);
  }
  for(int idx=t; idx<286; idx+=256) acc2[idx]=make_float2(0.f,0.f);
  __syncthreads();
  const float bb1=bias1[o];

  for(int jj=0;jj<20;jj+=2){
    // stage D for j=jj,jj+1 (contiguous 2660 floats, 16B-aligned for even jj)
    {
      const float4* src=(const float4*)(D1SJ + jj*1330);
      float4* dst=(float4*)&Dj[0][0];
      for(int idx=t; idx<665; idx+=256) dst[idx]=src[idx];
    }
    __syncthreads();
    // G build: 361 items (m,n), both j's
    for(int idx=t; idx<361; idx+=256){
      int m=idx/19-9, n=idx%19-9;
      int am=m<0?-m:m, an=n<0?-n:n;
      int l=am>an?am:an;
      int L=2*l+1;
      int zi=zbS[l]+(m+l)*L+(n+l);
      int m2=2*m+2;
      float2 a0=make_float2(0.f,0.f), a1=a0;
      for(; l<10; ++l){
        float2 zv=z[zi];
        float d0=Dj[0][zi], d1=Dj[1][zi];
        a0.x+=zv.x*d0; a0.y+=zv.y*d0;
        a1.x+=zv.x*d1; a1.y+=zv.y*d1;
        zi += L*L + 2*L + m2;
        L += 2;
      }
      G0[idx]=a0; G1[idx]=a1;
    }
    __syncthreads();
    // T: 380 items (mi,g): sum over n with e^{+i n g}
    for(int idx=t; idx<380; idx+=256){
      int mi=idx/20, g=idx%20;
      int k=(11*g)%20;
      float2 a0=make_float2(0.f,0.f), a1=a0;
      for(int ni=0;ni<19;++ni){
        float2 e=E20s[k];
        float2 g0=G0[mi*19+ni], g1=G1[mi*19+ni];
        a0.x += g0.x*e.x - g0.y*e.y;  a0.y += g0.x*e.y + g0.y*e.x;
        a1.x += g1.x*e.x - g1.y*e.y;  a1.y += g1.x*e.y + g1.y*e.x;
        k+=g; if(k>=20)k-=20;
      }
      T[0][idx]=a0; T[1][idx]=a1;
    }
    __syncthreads();
    // v: 400 items (a,g): Re sum over m of e^{+i m a} T, + bias, relu
    for(int idx=t; idx<400; idx+=256){
      int a=idx/20, g=idx%20;
      int k=(11*a)%20;
      float v0=0.f, v1=0.f;
      for(int mi=0;mi<19;++mi){
        float2 e=E20s[k];
        float2 t0=T[0][mi*20+g], t1=T[1][mi*20+g];
        v0 += t0.x*e.x - t0.y*e.y;
        v1 += t1.x*e.x - t1.y*e.y;
        k+=a; if(k>=20)k-=20;
      }
      v0+=bb1; v1+=bb1;
      v[0][idx]=v0>0.f?v0:0.f;
      v[1][idx]=v1>0.f?v1:0.f;
    }
    __syncthreads();
    // U: 220 items (a,nu): sum over g of v * conj(e^{+i nu g})
    for(int idx=t; idx<220; idx+=256){
      int a=idx/11, ni=idx%11;
      int nu=ni-5;
      int step=nu<0?nu+20:nu;
      int k=0;
      float2 a0=make_float2(0.f,0.f), a1=a0;
      for(int g=0;g<20;++g){
        float2 e=E20s[k];
        float v0=v[0][a*20+g], v1=v[1][a*20+g];
        a0.x += v0*e.x;  a0.y -= v0*e.y;
        a1.x += v1*e.x;  a1.y -= v1*e.y;
        k+=step; if(k>=20)k-=20;
      }
      U0[a*11+ni]=a0; U1[a*11+ni]=a1;
    }
    __syncthreads();
    // Fq: 121 items (mu,nu): sum over a of U * conj(e^{+i mu a})
    for(int idx=t; idx<121; idx+=256){
      int mi=idx/11, ni=idx%11;
      int mu=mi-5;
      int step=mu<0?mu+20:mu;
      int k=0;
      float2 a0=make_float2(0.f,0.f), a1=a0;
      for(int a=0;a<20;++a){
        float2 e=E20s[k];
        float2 u0=U0[a*11+ni], u1=U1[a*11+ni];
        a0.x += u0.x*e.x + u0.y*e.y;  a0.y += u0.y*e.x - u0.x*e.y;
        a1.x += u1.x*e.x + u1.y*e.y;  a1.y += u1.y*e.x - u1.x*e.y;
        k+=step; if(k>=20)k-=20;
      }
      Fq0[idx]=a0; Fq1[idx]=a1;
    }
    __syncthreads();
    // accumulate with W3 weights
    for(int idx=t; idx<286; idx+=256){
      int fi=map286S[idx];
      float w0=W3[jj*286+idx], w1=W3[(jj+1)*286+idx];
      float2 f0=Fq0[fi], f1=Fq1[fi];
      acc2[idx].x += w0*f0.x + w1*f1.x;
      acc2[idx].y += w0*f0.y + w1*f1.y;
    }
    __syncthreads();
  }
  for(int idx=t; idx<286; idx+=256){
    XH2[(b*286+idx)*F1 + o] = acc2[idx];
  }
}

// K2H layout: [o][s2][i]
__global__ void k2h_k(const float* __restrict__ k2, const float2* __restrict__ Y2,
                      float2* __restrict__ K2H){
  int idx=blockIdx.x*blockDim.x+threadIdx.x;
  if(idx>=NS2*F1*F2) return;
  int o=idx/(NS2*F1); int r=idx%(NS2*F1); int s=r/F1, i=r%F1;
  float2 acc=make_float2(0.f,0.f);
  const float* kr=k2+(i*F2+o)*192;
  for(int p=0;p<192;++p){
    float kv=kr[p];
    float2 y=Y2[p*NS2+s];
    acc.x+=kv*y.x; acc.y+=kv*y.y;
  }
  const float SC2f = 0.034722222222222224f;
  K2H[idx]=make_float2(acc.x*SC2f, acc.y*SC2f);
}

// fused2: z2 build (LDS-staged) + SO3 synthesis + relu + so3_integrate
__global__ __launch_bounds__(256) void fused2(
    const float2* __restrict__ XH2, const float2* __restrict__ K2H,
    const float* __restrict__ D2SJ, const float* __restrict__ WINT,
    const float2* __restrict__ E12, const float* __restrict__ bias2,
    float* __restrict__ FEAT){
  const int b=blockIdx.x, o=blockIdx.y, t=threadIdx.x;
  __shared__ __align__(16) float2 Xs[121*20];
  __shared__ __align__(16) float2 Ks[121*20];
  __shared__ float2 uni[1012];      // zp[2][286] during build; G2[4][121]+T2[4][132] in pipeline
  __shared__ float2 z2[286];
  __shared__ float2 E12s[12];
  __shared__ float  red[256];
  float2* zp0=uni;        float2* zp1=uni+286;
  float2* G2 =uni;                         // [4][121]
  float2* T2 =uni+484;                     // [4][132]

  const int gbase[4]={0,84,165,286};
  for(int grp=0; grp<3; ++grp){
    int row0=gbase[grp], rows=gbase[grp+1]-row0;
    {
      int cnt4=rows*10;  // float4 elements (rows*20 float2)
      const float4* xsrc=(const float4*)(XH2+(b*286+row0)*F1);
      const float4* ksrc=(const float4*)(K2H+(o*286+row0)*F1);
      float4* xd=(float4*)Xs; float4* kd=(float4*)Ks;
      for(int idx=t; idx<cnt4; idx+=256){ xd[idx]=xsrc[idx]; kd[idx]=ksrc[idx]; }
    }
    __syncthreads();
    for(int idx=t; idx<2*rows; idx+=256){
      int sl=idx>>1, ih=idx&1;
      int s2=row0+sl;
      int l=0; while(B2OFFc[l+1]<=s2) ++l;
      int r=s2-B2OFFc[l], L=2*l+1;
      int mi=r/L, ni=r%L;
      int xr0=(B2OFFc[l]-row0)+mi*L;
      int kr0=(B2OFFc[l]-row0)+ni*L;
      float2 acc=make_float2(0.f,0.f);
      for(int k=0;k<L;++k){
        const float2* xp=Xs+(xr0+k)*F1+ih*10;
        const float2* kp=Ks+(kr0+k)*F1+ih*10;
        #pragma unroll
        for(int i=0;i<10;++i){
          float2 xa=xp[i], kb=kp[i];
          acc.x += xa.x*kb.x + xa.y*kb.y;
          acc.y += xa.y*kb.x - xa.x*kb.y;
        }
      }
      if(ih==0) zp0[s2]=acc; else zp1[s2]=acc;
    }
    __syncthreads();
  }
  // merge partials into z2
  for(int idx=t; idx<286; idx+=256){
    z2[idx]=make_float2(zp0[idx].x+zp1[idx].x, zp0[idx].y+zp1[idx].y);
  }
  if(t<12) E12s[t]=E12[t];
  __syncthreads();

  float personal=0.f;
  const float b2=bias2[o];
  for(int jj=0;jj<12;jj+=4){
    // G2 build: 121 items, 4 j's
    for(int idx=t; idx<121; idx+=256){
      int m=idx/11-5, n=idx%11-5;
      int am=m<0?-m:m, an=n<0?-n:n;
      int l=am>an?am:an;
      int L=2*l+1;
      int zi=B2OFFc[l]+(m+l)*L+(n+l);
      int m2=2*m+2;
      float2 a0=make_float2(0.f,0.f), a1=a0, a2=a0, a3=a0;
      for(; l<6; ++l){
        float2 zv=z2[zi];
        float d0=D2SJ[jj*286+zi],     d1=D2SJ[(jj+1)*286+zi];
        float d2=D2SJ[(jj+2)*286+zi], d3=D2SJ[(jj+3)*286+zi];
        a0.x+=zv.x*d0; a0.y+=zv.y*d0;
        a1.x+=zv.x*d1; a1.y+=zv.y*d1;
        a2.x+=zv.x*d2; a2.y+=zv.y*d2;
        a3.x+=zv.x*d3; a3.y+=zv.y*d3;
        zi += L*L + 2*L + m2;
        L += 2;
      }
      G2[0*121+idx]=a0; G2[1*121+idx]=a1; G2[2*121+idx]=a2; G2[3*121+idx]=a3;
    }
    __syncthreads();
    // T2: 132 items (mi,gg)
    for(int idx=t; idx<132; idx+=256){
      int mi=idx/12, gg=idx%12;
      int k=(7*gg)%12;
      float2 a0=make_float2(0.f,0.f), a1=a0, a2=a0, a3=a0;
      for(int ni=0;ni<11;++ni){
        float2 e=E12s[k];
        float2 g0=G2[0*121+mi*11+ni], g1=G2[1*121+mi*11+ni];
        float2 g2=G2[2*121+mi*11+ni], g3=G2[3*121+mi*11+ni];
        a0.x+=g0.x*e.x-g0.y*e.y; a0.y+=g0.x*e.y+g0.y*e.x;
        a1.x+=g1.x*e.x-g1.y*e.y; a1.y+=g1.x*e.y+g1.y*e.x;
        a2.x+=g2.x*e.x-g2.y*e.y; a2.y+=g2.x*e.y+g2.y*e.x;
        a3.x+=g3.x*e.x-g3.y*e.y; a3.y+=g3.x*e.y+g3.y*e.x;
        k+=gg; if(k>=12)k-=12;
      }
      T2[0*132+idx]=a0; T2[1*132+idx]=a1; T2[2*132+idx]=a2; T2[3*132+idx]=a3;
    }
    __syncthreads();
    // val: 144 items (a,g), accumulate weighted relu
    float w0=WINT[jj], w1=WINT[jj+1], w2=WINT[jj+2], w3=WINT[jj+3];
    for(int idx=t; idx<144; idx+=256){
      int a=idx/12, g=idx%12;
      int k=(7*a)%12;
      float v0=0.f,v1=0.f,v2=0.f,v3=0.f;
      for(int mi=0;mi<11;++mi){
        float2 e=E12s[k];
        float2 t0=T2[0*132+mi*12+g], t1=T2[1*132+mi*12+g];
        float2 t2=T2[2*132+mi*12+g], t3=T2[3*132+mi*12+g];
        v0+=t0.x*e.x-t0.y*e.y;
        v1+=t1.x*e.x-t1.y*e.y;
        v2+=t2.x*e.x-t2.y*e.y;
        v3+=t3.x*e.x-t3.y*e.y;
        k+=a; if(k>=12)k-=12;
      }
      v0+=b2; v1+=b2; v2+=b2; v3+=b2;
      personal += w0*(v0>0.f?v0:0.f) + w1*(v1>0.f?v1:0.f)
                + w2*(v2>0.f?v2:0.f) + w3*(v3>0.f?v3:0.f);
    }
    __syncthreads();
  }
  red[t]=personal;
  __syncthreads();
  for(int s=128;s>0;s>>=1){
    if(t<s) red[t]+=red[t+s];
    __syncthreads();
  }
  if(t==0) FEAT[b*F2+o]=red[0];
}

__global__ void head_k(const float* __restrict__ FEAT, const float* __restrict__ w_out,
                       const float* __restrict__ b_lin, float* __restrict__ out){
  int idx=blockIdx.x*blockDim.x+threadIdx.x;
  if(idx>=BATCH*FOUT) return;
  int b=idx/FOUT, q=idx%FOUT;
  float acc=b_lin[q];
  for(int f=0;f<F2;++f) acc += FEAT[b*F2+f]*w_out[q*F2+f];
  out[idx]=acc;
}

extern "C" void kernel_launch(void* const* d_in, const int* in_sizes, int n_in,
                              void* d_out, int out_size, void* d_ws, size_t ws_size,
                              hipStream_t stream) {
  const float* x    =(const float*)d_in[0];
  const float* k1   =(const float*)d_in[1];
  const float* bias1=(const float*)d_in[2];
  const float* k2   =(const float*)d_in[3];
  const float* bias2=(const float*)d_in[4];
  const float* w_out=(const float*)d_in[5];
  const float* b_lin=(const float*)d_in[6];
  float* out=(float*)d_out;

  char* ws=(char*)d_ws;
  float*  A1  =(float* )(ws+0);        //  60*100 f        24000
  float2* Y1  =(float2*)(ws+24000);    //  24*100 c        19200
  float*  D1SJ=(float* )(ws+43200);    //  26600 f         106400
  float*  W3  =(float* )(ws+149600);   //  20*286 f        22880
  float2* Y2  =(float2*)(ws+172480);   //  192*286 c       439296
  float*  D2SJ=(float* )(ws+611776);   //  3432 f          13728
  float*  WINT=(float* )(ws+625504);   //  12 f            48
  float2* E60 =(float2*)(ws+625552);   //  60 c            480
  float2* E20 =(float2*)(ws+626032);   //  20 c            160
  float2* E12 =(float2*)(ws+626192);   //  12 c            96 (+pad)
  float2* XF  =(float2*)(ws+626304);   //  128*60*19 c     1167360
  float2* XHAT=(float2*)(ws+1793664);  //  [b][100] c      102400
  float2* K1H =(float2*)(ws+1896064);  //  [o][100] c      16000
  float2* XH2 =(float2*)(ws+1912064);  //  [b][286][20] c  5857280
  float2* K2H =(float2*)(ws+7769344);  //  [o][286][20] c  1830400
  float*  FEAT=(float* )(ws+9599744);  //  128*40 f        20480  -> 9620224 total

  (void)in_sizes; (void)n_in; (void)out_size; (void)ws_size;

  gen_A1 <<<(60*NS1+255)/256,256,0,stream>>>(A1);
  gen_Y1 <<<(24*NS1+255)/256,256,0,stream>>>(Y1);
  gen_D1S<<<(26600+255)/256,256,0,stream>>>(D1SJ);
  gen_W3 <<<(20*NS2+255)/256,256,0,stream>>>(W3);
  gen_Y2 <<<(192*NS2+255)/256,256,0,stream>>>(Y2);
  gen_D2S<<<(3432+255)/256,256,0,stream>>>(D2SJ);
  gen_misc<<<1,64,0,stream>>>(WINT,E60,E20,E12);

  dft60_k<<<(BATCH*60*19+255)/256,256,0,stream>>>(x,E60,XF);
  xhat_k <<<(BATCH*NS1+255)/256,256,0,stream>>>(XF,A1,XHAT);
  k1h_k  <<<(F1*NS1+255)/256,256,0,stream>>>(k1,Y1,K1H);
  dim3 g1(BATCH,F1);
  fused1 <<<g1,256,0,stream>>>(XHAT,K1H,D1SJ,W3,E20,bias1,XH2);
  k2h_k  <<<(NS2*F1*F2+255)/256,256,0,stream>>>(k2,Y2,K2H);
  dim3 g2(BATCH,F2);
  fused2 <<<g2,256,0,stream>>>(XH2,K2H,D2SJ,WINT,E12,bias2,FEAT);
  head_k <<<(BATCH*FOUT+255)/256,256,0,stream>>>(FEAT,w_out,b_lin,out);
}

// Round 4
// 467.936 us; speedup vs baseline: 3.8070x; 1.3560x over previous
//
#include <hip/hip_runtime.h>
#include <math.h>

#define PI_D 3.14159265358979323846

#define BATCH 128
#define F1 20
#define F2 40
#define FOUT 10
#define NS1 100   // sum_{l<10} (2l+1)
#define NS2 286   // sum_{l<6} (2l+1)^2
#define NH2 146   // Hermitian half count of NS2

__constant__ int ZB10c[11] = {0,1,10,35,84,165,286,455,680,969,1330};
__constant__ int B2OFFc[7] = {0,1,10,35,84,165,286};
__constant__ int HOFFc[7]  = {0,1,6,19,44,85,146};

// half-space H = { (m,n): n>0 } U { (m,n): n==0 && m>=0 }
// enumeration within l: first (n=0, m=0..l), then n=1..l blocks of full m rows
__device__ inline void h_decode(int h, int& l, int& m, int& n){
  l=0; while(HOFFc[l+1]<=h) ++l;
  int r=h-HOFFc[l], L=2*l+1;
  if(r<l+1){ n=0; m=r; }
  else { int q=r-(l+1); n=q/L+1; m=q%L-l; }
}

// ---------------- double-precision table generation helpers ----------------
__device__ inline double ipow_d(double x, int n){ double r=1.0; for(int i=0;i<n;++i) r*=x; return r; }
__device__ inline double dfact(int n){ double r=1.0; for(int i=2;i<=n;++i) r*=(double)i; return r; }

__device__ double wigd(int l, int mp, int m, double beta){
  double cb=cos(0.5*beta), sb=sin(0.5*beta);
  double pref=sqrt(dfact(l+mp)*dfact(l-mp)*dfact(l+m)*dfact(l-m));
  int s0 = (m-mp>0) ? (m-mp) : 0;
  int s1 = (l+m < l-mp) ? (l+m) : (l-mp);
  double acc=0.0;
  for(int s=s0;s<=s1;++s){
    double den=dfact(l+m-s)*dfact(s)*dfact(mp-m+s)*dfact(l-mp-s);
    double t=ipow_d(cb,2*l+m-mp-2*s)*ipow_d(sb,mp-m+2*s)/den;
    acc += ((mp-m+s)&1)? -t : t;
  }
  return pref*acc;
}

__device__ double dhw(int b, int j){
  double beta=PI_D*(2*j+1)/(4.0*b);
  double s=0.0;
  for(int k=0;k<b;++k) s += sin((2*k+1)*beta)/(2*k+1);
  return (2.0/b)*sin(beta)*s;
}

__device__ inline float2 cmulc(float2 a, float2 b){ // a * conj(b)
  return make_float2(a.x*b.x + a.y*b.y, a.y*b.x - a.x*b.y);
}

// ---------------- single merged table-generation kernel ----------------
__global__ void gen_all(float* A1, float2* Y1, float* D1SJ, float* W3H,
                        float2* Y2, float* D2SJ, float* WINT,
                        float2* E60, float2* E20, float2* E12){
  int blk=blockIdx.x, t=threadIdx.x;
  if(blk<24){                     // A1: [j][s1], 60x100
    int idx=blk*256+t; if(idx>=6000) return;
    int j=idx/NS1, s=idx%NS1;
    int l=0; while((l+1)*(l+1)<=s) ++l;
    int m=s-l*l-l;
    double beta=PI_D*(2*j+1)/120.0;
    A1[idx]=(float)(wigd(l,m,0,beta)*dhw(30,j)*(2.0*PI_D/60.0));
  } else if(blk<34){              // Y1: [p][s1], 24x100
    int idx=(blk-24)*256+t; if(idx>=2400) return;
    int p=idx/NS1, s=idx%NS1;
    int l=0; while((l+1)*(l+1)<=s) ++l;
    int m=s-l*l-l;
    int bi=p/8, ai=p%8;
    double beta=(bi+1)*(PI_D/8.0)/3.0;
    double alpha=2.0*PI_D*ai/8.0;
    double d=wigd(l,m,0,beta);
    double ph=-alpha*m;
    Y1[idx]=make_float2((float)(d*cos(ph)),(float)(d*sin(ph)));
  } else if(blk<138){             // D1SJ: [j][1330]
    int idx=(blk-34)*256+t; if(idx>=26600) return;
    int j=idx/1330, s=idx%1330;
    int l=0; while(ZB10c[l+1]<=s) ++l;
    int r=s-ZB10c[l]; int L=2*l+1;
    int mi=r/L, ni=r%L;
    double beta=PI_D*(2*j+1)/40.0;
    D1SJ[idx]=(float)((2*l+1)*wigd(l,mi-l,ni-l,beta));
  } else if(blk<150){             // W3H: [j][146] half-layout
    int idx=(blk-138)*256+t; if(idx>=20*NH2) return;
    int j=idx/NH2, h=idx%NH2;
    int l,m,n; h_decode(h,l,m,n);
    double beta=PI_D*(2*j+1)/40.0;
    double c=2.0*PI_D/20.0;
    W3H[idx]=(float)(wigd(l,m,n,beta)*dhw(10,j)*c*c);
  } else if(blk<365){             // Y2: [p][286]
    int idx=(blk-150)*256+t; if(idx>=192*NS2) return;
    int p=idx/NS2, s=idx%NS2;
    int l=0; while(B2OFFc[l+1]<=s) ++l;
    int r=s-B2OFFc[l]; int L=2*l+1;
    int m=r/L-l, n=r%L-l;
    int bi=p/64, ai=(p/8)%8, gi=p%8;
    double beta=(bi+1)*(PI_D/8.0)/3.0;
    double alpha=2.0*PI_D*ai/8.0;
    double gamma=2.0*PI_D*gi/8.0 - alpha;
    double d=wigd(l,m,n,beta);
    double ph=-(alpha*m+gamma*n);
    Y2[idx]=make_float2((float)(d*cos(ph)),(float)(d*sin(ph)));
  } else if(blk<379){             // D2SJ: [j][286]
    int idx=(blk-365)*256+t; if(idx>=3432) return;
    int j=idx/286, s=idx%286;
    int l=0; while(B2OFFc[l+1]<=s) ++l;
    int r=s-B2OFFc[l]; int L=2*l+1;
    int mi=r/L, ni=r%L;
    double beta=PI_D*(2*j+1)/24.0;
    D2SJ[idx]=(float)((2*l+1)*wigd(l,mi-l,ni-l,beta));
  } else {                        // misc
    if(t<12){ double c=2.0*PI_D/12.0; WINT[t]=(float)(dhw(6,t)*c*c); }
    if(t<60){ double a=2.0*PI_D*t/60.0; E60[t]=make_float2((float)cos(a),(float)sin(a)); }
    if(t<20){ double a=2.0*PI_D*t/20.0; E20[t]=make_float2((float)cos(a),(float)sin(a)); }
    if(t<12){ double a=2.0*PI_D*t/12.0; E12[t]=make_float2((float)cos(a),(float)sin(a)); }
  }
}

// ---------------- front: per-b DFT + S2 analysis (XF in LDS), plus k1h ----------------
__global__ __launch_bounds__(256) void front_k(const float* __restrict__ x,
    const float* __restrict__ k1, const float2* __restrict__ E60,
    const float* __restrict__ A1, const float2* __restrict__ Y1,
    float2* __restrict__ XHAT, float2* __restrict__ K1H){
  __shared__ float xs[3600];
  __shared__ float2 E60s[60];
  __shared__ float2 XFs[1140];     // [j][mi], mi = m+9
  int blk=blockIdx.x, t=threadIdx.x;
  if(blk<128){
    if(t<60) E60s[t]=E60[t];
    {
      const float4* src=(const float4*)(x+blk*3600);
      float4* dst=(float4*)xs;
      for(int i=t;i<900;i+=256) dst[i]=src[i];
    }
    __syncthreads();
    for(int idx=t; idx<1140; idx+=256){
      int j=idx/19, mi=idx%19;
      int step=(mi<9)? mi+51 : mi-9;  // (m mod 60), m=mi-9
      const float* xr=xs+j*60;
      float2 acc=make_float2(0.f,0.f);
      int k=0;
      for(int a=0;a<60;++a){
        float2 e=E60s[k]; float xv=xr[a];
        acc.x+=xv*e.x; acc.y-=xv*e.y;
        k+=step; if(k>=60)k-=60;
      }
      XFs[idx]=acc;
    }
    __syncthreads();
    for(int s=t; s<100; s+=256){
      int l=0; while((l+1)*(l+1)<=s) ++l;
      int m=s-l*l-l;
      const float2* xf=&XFs[m+9];
      float2 acc=make_float2(0.f,0.f);
      for(int j=0;j<60;++j){
        float a1=A1[j*NS1+s];
        float2 v=xf[j*19];
        acc.x+=a1*v.x; acc.y+=a1*v.y;
      }
      XHAT[blk*NS1+s]=acc;
    }
  } else {
    int idx=(blk-128)*256+t;
    if(idx<F1*NS1){
      int o=idx/NS1, s=idx%NS1;
      float2 acc=make_float2(0.f,0.f);
      for(int p=0;p<24;++p){
        float kv=k1[o*24+p];
        float2 y=Y1[p*NS1+s];
        acc.x+=kv*y.x; acc.y+=kv*y.y;
      }
      const float SC1f = 0.06123724356957945f;
      K1H[idx]=make_float2(acc.x*SC1f, acc.y*SC1f);
    }
  }
}

// fused1: conv1 SO3 synthesis + relu + conv2-analysis, Hermitian-half everywhere.
// XH2 layout: [b][s2][i]
__global__ __launch_bounds__(256) void fused1(
    const float2* __restrict__ XHAT, const float2* __restrict__ K1H,
    const float* __restrict__ D1SJ, const float* __restrict__ W3H,
    const float2* __restrict__ E20, const float* __restrict__ bias1,
    float2* __restrict__ XH2){
  const int b=blockIdx.x, o=blockIdx.y, t=threadIdx.x;
  __shared__ float2 z[1330];
  __shared__ __align__(16) float Dj[2][1330];
  __shared__ float2 G[2][190];     // rows m=0..9, cols n=-9..9 (col idx n+9)
  __shared__ float2 S[2][180];     // m=1..9 x g=0..19 : 2*sum_n G e^{ing}
  __shared__ float  T0[2][20];     // Re T(0,g)
  __shared__ float  v[2][400];     // a x g
  __shared__ float2 U[2][120];     // a x nu(0..5)
  __shared__ float2 Fq[2][61];     // half-list order
  __shared__ float2 acc2[146];
  __shared__ float2 E20s[20];

  if(t<20){ E20s[t]=E20[t]; }
  for(int idx=t; idx<1330; idx+=256){
    int l=0; while(ZB10c[l+1]<=idx) ++l;
    int r=idx-ZB10c[l], L=2*l+1;
    int mi=r/L, ni=r%L;
    float2 xa=XHAT[b*NS1 + l*l+mi];
    float2 kb=K1H[o*NS1 + l*l+ni];
    z[idx]=cmulc(xa,kb);
  }
  for(int idx=t; idx<146; idx+=256) acc2[idx]=make_float2(0.f,0.f);
  {
    const float4* src=(const float4*)D1SJ;
    float4* dst=(float4*)&Dj[0][0];
    for(int idx=t; idx<665; idx+=256) dst[idx]=src[idx];
  }
  __syncthreads();
  const float bb1=bias1[o];

  for(int jj=0;jj<20;jj+=2){
    // A: G build, half-space by m (181 items)
    for(int idx=t; idx<181; idx+=256){
      int m,n;
      if(idx<10){ m=0; n=idx; }
      else { int q=idx-10; m=q/19+1; n=q%19-9; }
      int an=n<0?-n:n;
      int l=m>an?m:an;
      int L=2*l+1;
      int zi=ZB10c[l]+(m+l)*L+(n+l);
      int m2=2*m+2;
      float2 a0=make_float2(0.f,0.f), a1=a0;
      for(; l<10; ++l){
        float2 zv=z[zi];
        float d0=Dj[0][zi], d1=Dj[1][zi];
        a0.x+=zv.x*d0; a0.y+=zv.y*d0;
        a1.x+=zv.x*d1; a1.y+=zv.y*d1;
        zi += L*L + 2*L + m2;
        L += 2;
      }
      int gi=m*19+(n+9);
      G[0][gi]=a0; G[1][gi]=a1;
    }
    __syncthreads();
    // B: S_m(g) = 2*sum_{n=-9..9} G(m,n) e^{ing} for m=1..9 (180) + ReT0(g) (20)
    for(int idx=t; idx<200; idx+=256){
      if(idx<180){
        int m=idx/20+1, g=idx%20;
        int k=(11*g)%20;  // n=-9 start
        const float2* Gr0=&G[0][m*19];
        const float2* Gr1=&G[1][m*19];
        float2 a0=make_float2(0.f,0.f), a1=a0;
        for(int ni=0;ni<19;++ni){
          float2 e=E20s[k];
          float2 g0=Gr0[ni], g1=Gr1[ni];
          a0.x += g0.x*e.x - g0.y*e.y;  a0.y += g0.x*e.y + g0.y*e.x;
          a1.x += g1.x*e.x - g1.y*e.y;  a1.y += g1.x*e.y + g1.y*e.x;
          k+=g; if(k>=20)k-=20;
        }
        S[0][(m-1)*20+g]=make_float2(2.f*a0.x, 2.f*a0.y);
        S[1][(m-1)*20+g]=make_float2(2.f*a1.x, 2.f*a1.y);
      } else {
        int g=idx-180;
        float r0=G[0][9].x, r1=G[1][9].x;   // n=0
        int k=g;  // n=1 start
        for(int n=1;n<10;++n){
          float2 e=E20s[k];
          float2 g0=G[0][9+n], g1=G[1][9+n];
          r0 += 2.f*(g0.x*e.x - g0.y*e.y);
          r1 += 2.f*(g1.x*e.x - g1.y*e.y);
          k+=g; if(k>=20)k-=20;
        }
        T0[0][g]=r0; T0[1][g]=r1;
      }
    }
    __syncthreads();
    // C: spatial v(a,g) = ReT0 + sum_{m>=1} Re[S e^{ima}], bias, relu (400)
    for(int idx=t; idx<400; idx+=256){
      int a=idx/20, g=idx%20;
      float v0=T0[0][g], v1=T0[1][g];
      int k=a;  // m=1 start
      for(int m=1;m<10;++m){
        float2 e=E20s[k];
        float2 s0=S[0][(m-1)*20+g], s1=S[1][(m-1)*20+g];
        v0 += s0.x*e.x - s0.y*e.y;
        v1 += s1.x*e.x - s1.y*e.y;
        k+=a; if(k>=20)k-=20;
      }
      v0+=bb1; v1+=bb1;
      v[0][idx]=v0>0.f?v0:0.f;
      v[1][idx]=v1>0.f?v1:0.f;
    }
    __syncthreads();
    // D: U(a,nu), nu=0..5 (120)
    for(int idx=t; idx<120; idx+=256){
      int a=idx/6, nu=idx%6;
      const float* vr0=&v[0][a*20];
      const float* vr1=&v[1][a*20];
      int k=0;
      float2 a0=make_float2(0.f,0.f), a1=a0;
      for(int g=0;g<20;++g){
        float2 e=E20s[k];
        float x0=vr0[g], x1=vr1[g];
        a0.x+=x0*e.x; a0.y-=x0*e.y;
        a1.x+=x1*e.x; a1.y-=x1*e.y;
        k+=nu; if(k>=20)k-=20;
      }
      U[0][idx]=a0; U[1][idx]=a1;
    }
    __syncthreads();
    // E: Fq half-list (61)
    for(int idx=t; idx<61; idx+=256){
      int mu,nu;
      if(idx<6){ mu=idx; nu=0; }
      else { int q=idx-6; nu=q/11+1; mu=q%11-5; }
      int step=mu<0?mu+20:mu;
      int k=0;
      float2 a0=make_float2(0.f,0.f), a1=a0;
      for(int a=0;a<20;++a){
        float2 e=E20s[k];
        float2 u0=U[0][a*6+nu], u1=U[1][a*6+nu];
        a0.x+=u0.x*e.x+u0.y*e.y; a0.y+=u0.y*e.x-u0.x*e.y;
        a1.x+=u1.x*e.x+u1.y*e.y; a1.y+=u1.y*e.x-u1.x*e.y;
        k+=step; if(k>=20)k-=20;
      }
      Fq[0][idx]=a0; Fq[1][idx]=a1;
    }
    __syncthreads();
    // F: accumulate half-s2 with W3H (146) + stage next Dj pair
    for(int idx=t; idx<146; idx+=256){
      int l,m,n; h_decode(idx,l,m,n);
      int fh=(n==0)? m : 6+(n-1)*11+(m+5);
      float w0=W3H[jj*NH2+idx], w1=W3H[(jj+1)*NH2+idx];
      float2 f0=Fq[0][fh], f1=Fq[1][fh];
      acc2[idx].x += w0*f0.x + w1*f1.x;
      acc2[idx].y += w0*f0.y + w1*f1.y;
    }
    if(jj<18){
      const float4* src=(const float4*)(D1SJ+(jj+2)*1330);
      float4* dst=(float4*)&Dj[0][0];
      for(int idx=t; idx<665; idx+=256) dst[idx]=src[idx];
    }
    __syncthreads();
  }
  // expand half -> full XH2 by conjugation
  for(int h=t; h<146; h+=256){
    int l,m,n; h_decode(h,l,m,n);
    int L=2*l+1;
    int s2 =B2OFFc[l]+(m+l)*L+(n+l);
    int s2p=B2OFFc[l]+(l-m)*L+(l-n);
    float2 a=acc2[h];
    float sg=((m+n)&1)? -1.f : 1.f;
    XH2[(b*286+s2 )*F1+o]=a;
    XH2[(b*286+s2p)*F1+o]=make_float2(sg*a.x, -sg*a.y);
  }
}

// K2H layout: [o][s2][i]
__global__ void k2h_k(const float* __restrict__ k2, const float2* __restrict__ Y2,
                      float2* __restrict__ K2H){
  int idx=blockIdx.x*blockDim.x+threadIdx.x;
  if(idx>=NS2*F1*F2) return;
  int o=idx/(NS2*F1); int r=idx%(NS2*F1); int s=r/F1, i=r%F1;
  float2 acc=make_float2(0.f,0.f);
  const float* kr=k2+(i*F2+o)*192;
  for(int p=0;p<192;++p){
    float kv=kr[p];
    float2 y=Y2[p*NS2+s];
    acc.x+=kv*y.x; acc.y+=kv*y.y;
  }
  const float SC2f = 0.034722222222222224f;
  K2H[idx]=make_float2(acc.x*SC2f, acc.y*SC2f);
}

// fused2: z2 half-build + Hermitian SO3 synthesis + relu + so3_integrate
__global__ __launch_bounds__(256) void fused2(
    const float2* __restrict__ XH2, const float2* __restrict__ K2H,
    const float* __restrict__ D2SJ, const float* __restrict__ WINT,
    const float2* __restrict__ E12, const float* __restrict__ bias2,
    float* __restrict__ FEAT){
  const int b=blockIdx.x, o=blockIdx.y, t=threadIdx.x;
  __shared__ __align__(16) float2 Xs[121*20];
  __shared__ __align__(16) float2 Ks[121*20];
  __shared__ float2 uni[1144];     // zp[4][286] during build; G2/S2/T02 in pipeline
  __shared__ float2 z2[286];
  __shared__ float2 E12s[12];
  __shared__ float  red[256];
  float2* zp = uni;                // [4][286]
  float2* G2 = uni;                // [4][66]: rows m=0..5, cols n+5
  float2* S2 = uni+264;            // [4][60]: m=1..5 x g : 2*sum_n G2 e^{ing}
  float*  T02= (float*)(uni+504);  // [4][12]

  if(t<12){ E12s[t]=E12[t]; }
  const int gb[4]={0,84,165,286};
  const int hb[4]={0,44,85,146};
  for(int grp=0; grp<3; ++grp){
    int row0=gb[grp], rows=gb[grp+1]-row0;
    {
      int cnt4=rows*10;
      const float4* xsrc=(const float4*)(XH2+(size_t)(b*286+row0)*F1);
      const float4* ksrc=(const float4*)(K2H+(size_t)(o*286+row0)*F1);
      float4* xd=(float4*)Xs; float4* kd=(float4*)Ks;
      for(int i=t;i<cnt4;i+=256){ xd[i]=xsrc[i]; kd[i]=ksrc[i]; }
    }
    __syncthreads();
    int nh=hb[grp+1]-hb[grp];
    for(int idx=t; idx<4*nh; idx+=256){
      int hl=idx>>2, iq=idx&3;
      int h=hb[grp]+hl;
      int l,m,n; h_decode(h,l,m,n);
      int L=2*l+1;
      int s2=B2OFFc[l]+(m+l)*L+(n+l);
      int xr0=(B2OFFc[l]-row0)+(m+l)*L;
      int kr0=(B2OFFc[l]-row0)+(n+l)*L;
      float2 acc=make_float2(0.f,0.f);
      for(int k=0;k<L;++k){
        const float2* xp=Xs+(xr0+k)*F1+iq*5;
        const float2* kp=Ks+(kr0+k)*F1+iq*5;
        #pragma unroll
        for(int i=0;i<5;++i){
          float2 xa=xp[i], kb=kp[i];
          acc.x += xa.x*kb.x + xa.y*kb.y;
          acc.y += xa.y*kb.x - xa.x*kb.y;
        }
      }
      zp[iq*286+s2]=acc;
    }
    __syncthreads();
  }
  // merge partials + Hermitian fill
  for(int idx=t; idx<146; idx+=256){
    int l,m,n; h_decode(idx,l,m,n);
    int L=2*l+1;
    int s2 =B2OFFc[l]+(m+l)*L+(n+l);
    int s2p=B2OFFc[l]+(l-m)*L+(l-n);
    float2 a;
    a.x=zp[0*286+s2].x+zp[1*286+s2].x+zp[2*286+s2].x+zp[3*286+s2].x;
    a.y=zp[0*286+s2].y+zp[1*286+s2].y+zp[2*286+s2].y+zp[3*286+s2].y;
    z2[s2]=a;
    float sg=((m+n)&1)?-1.f:1.f;
    z2[s2p]=make_float2(sg*a.x,-sg*a.y);
  }
  __syncthreads();

  float personal=0.f;
  const float b2=bias2[o];
  for(int jj=0;jj<12;jj+=4){
    // G2: half rows m>=0 (61 items), 4 j's
    for(int idx=t; idx<61; idx+=256){
      int m,n;
      if(idx<6){ m=0; n=idx; }
      else { int q=idx-6; m=q/11+1; n=q%11-5; }
      int an=n<0?-n:n;
      int l=m>an?m:an;
      int L=2*l+1;
      int zi=B2OFFc[l]+(m+l)*L+(n+l);
      int m2=2*m+2;
      float2 a0=make_float2(0.f,0.f), a1=a0, a2=a0, a3=a0;
      for(; l<6; ++l){
        float2 zv=z2[zi];
        float d0=D2SJ[jj*286+zi],     d1=D2SJ[(jj+1)*286+zi];
        float d2=D2SJ[(jj+2)*286+zi], d3=D2SJ[(jj+3)*286+zi];
        a0.x+=zv.x*d0; a0.y+=zv.y*d0;
        a1.x+=zv.x*d1; a1.y+=zv.y*d1;
        a2.x+=zv.x*d2; a2.y+=zv.y*d2;
        a3.x+=zv.x*d3; a3.y+=zv.y*d3;
        zi += L*L + 2*L + m2;
        L += 2;
      }
      int gi=m*11+(n+5);
      G2[0*66+gi]=a0; G2[1*66+gi]=a1; G2[2*66+gi]=a2; G2[3*66+gi]=a3;
    }
    __syncthreads();
    // S2_m(g) = 2*sum_n G2(m,n) e^{ing} for m=1..5 (60) + T02 (12)
    for(int idx=t; idx<72; idx+=256){
      if(idx<60){
        int m=idx/12+1, g=idx%12;
        int k=(7*g)%12;  // n=-5 start
        float2 a0=make_float2(0.f,0.f), a1=a0, a2=a0, a3=a0;
        const float2* g0r=&G2[0*66+m*11];
        const float2* g1r=&G2[1*66+m*11];
        const float2* g2r=&G2[2*66+m*11];
        const float2* g3r=&G2[3*66+m*11];
        for(int ni=0;ni<11;++ni){
          float2 e=E12s[k];
          float2 g0=g0r[ni], g1=g1r[ni], g2=g2r[ni], g3=g3r[ni];
          a0.x+=g0.x*e.x-g0.y*e.y; a0.y+=g0.x*e.y+g0.y*e.x;
          a1.x+=g1.x*e.x-g1.y*e.y; a1.y+=g1.x*e.y+g1.y*e.x;
          a2.x+=g2.x*e.x-g2.y*e.y; a2.y+=g2.x*e.y+g2.y*e.x;
          a3.x+=g3.x*e.x-g3.y*e.y; a3.y+=g3.x*e.y+g3.y*e.x;
          k+=g; if(k>=12)k-=12;
        }
        int si=(m-1)*12+g;
        S2[0*60+si]=make_float2(2.f*a0.x,2.f*a0.y);
        S2[1*60+si]=make_float2(2.f*a1.x,2.f*a1.y);
        S2[2*60+si]=make_float2(2.f*a2.x,2.f*a2.y);
        S2[3*60+si]=make_float2(2.f*a3.x,2.f*a3.y);
      } else {
        int g=idx-60;
        float r0=G2[0*66+5].x, r1=G2[1*66+5].x, r2=G2[2*66+5].x, r3=G2[3*66+5].x;
        int k=g;
        for(int n=1;n<6;++n){
          float2 e=E12s[k];
          float2 g0=G2[0*66+5+n], g1=G2[1*66+5+n], g2=G2[2*66+5+n], g3=G2[3*66+5+n];
          r0+=2.f*(g0.x*e.x-g0.y*e.y);
          r1+=2.f*(g1.x*e.x-g1.y*e.y);
          r2+=2.f*(g2.x*e.x-g2.y*e.y);
          r3+=2.f*(g3.x*e.x-g3.y*e.y);
          k+=g; if(k>=12)k-=12;
        }
        T02[0*12+g]=r0; T02[1*12+g]=r1; T02[2*12+g]=r2; T02[3*12+g]=r3;
      }
    }
    __syncthreads();
    // val: 144 items
    float w0=WINT[jj],w1=WINT[jj+1],w2=WINT[jj+2],w3=WINT[jj+3];
    if(t<144){
      int a=t/12, g=t%12;
      float v0=T02[0*12+g], v1=T02[1*12+g], v2=T02[2*12+g], v3=T02[3*12+g];
      int k=a;
      for(int m=1;m<6;++m){
        float2 e=E12s[k];
        int si=(m-1)*12+g;
        float2 s0=S2[0*60+si], s1=S2[1*60+si], s2v=S2[2*60+si], s3=S2[3*60+si];
        v0+=s0.x*e.x-s0.y*e.y;
        v1+=s1.x*e.x-s1.y*e.y;
        v2+=s2v.x*e.x-s2v.y*e.y;
        v3+=s3.x*e.x-s3.y*e.y;
        k+=a; if(k>=12)k-=12;
      }
      v0+=b2; v1+=b2; v2+=b2; v3+=b2;
      personal += w0*(v0>0.f?v0:0.f) + w1*(v1>0.f?v1:0.f)
                + w2*(v2>0.f?v2:0.f) + w3*(v3>0.f?v3:0.f);
    }
    __syncthreads();
  }
  red[t]=personal;
  __syncthreads();
  for(int s=128;s>0;s>>=1){
    if(t<s) red[t]+=red[t+s];
    __syncthreads();
  }
  if(t==0) FEAT[b*F2+o]=red[0];
}

__global__ void head_k(const float* __restrict__ FEAT, const float* __restrict__ w_out,
                       const float* __restrict__ b_lin, float* __restrict__ out){
  int idx=blockIdx.x*blockDim.x+threadIdx.x;
  if(idx>=BATCH*FOUT) return;
  int b=idx/FOUT, q=idx%FOUT;
  float acc=b_lin[q];
  for(int f=0;f<F2;++f) acc += FEAT[b*F2+f]*w_out[q*F2+f];
  out[idx]=acc;
}

extern "C" void kernel_launch(void* const* d_in, const int* in_sizes, int n_in,
                              void* d_out, int out_size, void* d_ws, size_t ws_size,
                              hipStream_t stream) {
  const float* x    =(const float*)d_in[0];
  const float* k1   =(const float*)d_in[1];
  const float* bias1=(const float*)d_in[2];
  const float* k2   =(const float*)d_in[3];
  const float* bias2=(const float*)d_in[4];
  const float* w_out=(const float*)d_in[5];
  const float* b_lin=(const float*)d_in[6];
  float* out=(float*)d_out;

  char* ws=(char*)d_ws;
  float*  A1  =(float* )(ws+0);        //  6000 f       24000
  float2* Y1  =(float2*)(ws+24000);    //  2400 c       19200
  float*  D1SJ=(float* )(ws+43200);    //  26600 f      106400
  float*  W3H =(float* )(ws+149600);   //  20*146 f     11680
  float2* Y2  =(float2*)(ws+161280);   //  192*286 c    439296
  float*  D2SJ=(float* )(ws+600576);   //  3432 f       13728
  float*  WINT=(float* )(ws+614304);   //  12 f         48
  float2* E60 =(float2*)(ws+614352);   //  60 c         480
  float2* E20 =(float2*)(ws+614832);   //  20 c         160
  float2* E12 =(float2*)(ws+614992);   //  12 c         96 (+16 pad)
  float2* XHAT=(float2*)(ws+615104);   //  [b][100] c   102400
  float2* K1H =(float2*)(ws+717504);   //  [o][100] c   16000
  float2* XH2 =(float2*)(ws+733504);   //  [b][286][20] 5857280
  float2* K2H =(float2*)(ws+6590784);  //  [o][286][20] 1830400
  float*  FEAT=(float* )(ws+8421184);  //  128*40 f     20480  -> 8441664 total

  (void)in_sizes; (void)n_in; (void)out_size; (void)ws_size;

  gen_all<<<380,256,0,stream>>>(A1,Y1,D1SJ,W3H,Y2,D2SJ,WINT,E60,E20,E12);
  front_k<<<136,256,0,stream>>>(x,k1,E60,A1,Y1,XHAT,K1H);
  dim3 g1(BATCH,F1);
  fused1<<<g1,256,0,stream>>>(XHAT,K1H,D1SJ,W3H,E20,bias1,XH2);
  k2h_k<<<(NS2*F1*F2+255)/256,256,0,stream>>>(k2,Y2,K2H);
  dim3 g2(BATCH,F2);
  fused2<<<g2,256,0,stream>>>(XH2,K2H,D2SJ,WINT,E12,bias2,FEAT);
  head_k<<<(BATCH*FOUT+255)/256,256,0,stream>>>(FEAT,w_out,b_lin,out);
}

// Round 5
// 360.568 us; speedup vs baseline: 4.9406x; 1.2978x over previous
//
#include <hip/hip_runtime.h>
#include <math.h>

#define PI_D 3.14159265358979323846

#define BATCH 128
#define F1 20
#define F2 40
#define FOUT 10
#define NS1 100   // sum_{l<10} (2l+1)
#define NS2 286   // sum_{l<6} (2l+1)^2
#define NH2 146   // Hermitian half count of NS2

__constant__ int ZB10c[11] = {0,1,10,35,84,165,286,455,680,969,1330};
__constant__ int B2OFFc[7] = {0,1,10,35,84,165,286};
__constant__ int HOFFc[7]  = {0,1,6,19,44,85,146};

// wave-synchronous phase fence: LDS ops of one wave complete in order; this
// stops the compiler reordering loads before prior lanes' stores.
#define WFENCE do{ __builtin_amdgcn_sched_barrier(0); \
  asm volatile("s_waitcnt lgkmcnt(0)" ::: "memory"); \
  __builtin_amdgcn_sched_barrier(0); }while(0)

// half-space H = { (m,n): n>0 } U { (m,n): n==0 && m>=0 }
__device__ inline void h_decode(int h, int& l, int& m, int& n){
  l=0; while(HOFFc[l+1]<=h) ++l;
  int r=h-HOFFc[l], L=2*l+1;
  if(r<l+1){ n=0; m=r; }
  else { int q=r-(l+1); n=q/L+1; m=q%L-l; }
}

// ---------------- double-precision table generation helpers ----------------
__device__ inline double ipow_d(double x, int n){ double r=1.0; for(int i=0;i<n;++i) r*=x; return r; }
__device__ inline double dfact(int n){ double r=1.0; for(int i=2;i<=n;++i) r*=(double)i; return r; }

__device__ double wigd(int l, int mp, int m, double beta){
  double cb=cos(0.5*beta), sb=sin(0.5*beta);
  double pref=sqrt(dfact(l+mp)*dfact(l-mp)*dfact(l+m)*dfact(l-m));
  int s0 = (m-mp>0) ? (m-mp) : 0;
  int s1 = (l+m < l-mp) ? (l+m) : (l-mp);
  double acc=0.0;
  for(int s=s0;s<=s1;++s){
    double den=dfact(l+m-s)*dfact(s)*dfact(mp-m+s)*dfact(l-mp-s);
    double t=ipow_d(cb,2*l+m-mp-2*s)*ipow_d(sb,mp-m+2*s)/den;
    acc += ((mp-m+s)&1)? -t : t;
  }
  return pref*acc;
}

__device__ double dhw(int b, int j){
  double beta=PI_D*(2*j+1)/(4.0*b);
  double s=0.0;
  for(int k=0;k<b;++k) s += sin((2*k+1)*beta)/(2*k+1);
  return (2.0/b)*sin(beta)*s;
}

__device__ inline float2 cmulc(float2 a, float2 b){ // a * conj(b)
  return make_float2(a.x*b.x + a.y*b.y, a.y*b.x - a.x*b.y);
}

// ---------------- single merged table-generation kernel ----------------
__global__ void gen_all(float* A1, float2* Y1, float* D1SJ, float* W3H,
                        float2* Y2, float* D2SJ, float* WINT,
                        float2* E60, float2* E20, float2* E12){
  int blk=blockIdx.x, t=threadIdx.x;
  if(blk<24){                     // A1: [j][s1], 60x100
    int idx=blk*256+t; if(idx>=6000) return;
    int j=idx/NS1, s=idx%NS1;
    int l=0; while((l+1)*(l+1)<=s) ++l;
    int m=s-l*l-l;
    double beta=PI_D*(2*j+1)/120.0;
    A1[idx]=(float)(wigd(l,m,0,beta)*dhw(30,j)*(2.0*PI_D/60.0));
  } else if(blk<34){              // Y1: [p][s1], 24x100
    int idx=(blk-24)*256+t; if(idx>=2400) return;
    int p=idx/NS1, s=idx%NS1;
    int l=0; while((l+1)*(l+1)<=s) ++l;
    int m=s-l*l-l;
    int bi=p/8, ai=p%8;
    double beta=(bi+1)*(PI_D/8.0)/3.0;
    double alpha=2.0*PI_D*ai/8.0;
    double d=wigd(l,m,0,beta);
    double ph=-alpha*m;
    Y1[idx]=make_float2((float)(d*cos(ph)),(float)(d*sin(ph)));
  } else if(blk<138){             // D1SJ: [j][1330]
    int idx=(blk-34)*256+t; if(idx>=26600) return;
    int j=idx/1330, s=idx%1330;
    int l=0; while(ZB10c[l+1]<=s) ++l;
    int r=s-ZB10c[l]; int L=2*l+1;
    int mi=r/L, ni=r%L;
    double beta=PI_D*(2*j+1)/40.0;
    D1SJ[idx]=(float)((2*l+1)*wigd(l,mi-l,ni-l,beta));
  } else if(blk<150){             // W3H: [j][146] half-layout
    int idx=(blk-138)*256+t; if(idx>=20*NH2) return;
    int j=idx/NH2, h=idx%NH2;
    int l,m,n; h_decode(h,l,m,n);
    double beta=PI_D*(2*j+1)/40.0;
    double c=2.0*PI_D/20.0;
    W3H[idx]=(float)(wigd(l,m,n,beta)*dhw(10,j)*c*c);
  } else if(blk<365){             // Y2: [p][286]
    int idx=(blk-150)*256+t; if(idx>=192*NS2) return;
    int p=idx/NS2, s=idx%NS2;
    int l=0; while(B2OFFc[l+1]<=s) ++l;
    int r=s-B2OFFc[l]; int L=2*l+1;
    int m=r/L-l, n=r%L-l;
    int bi=p/64, ai=(p/8)%8, gi=p%8;
    double beta=(bi+1)*(PI_D/8.0)/3.0;
    double alpha=2.0*PI_D*ai/8.0;
    double gamma=2.0*PI_D*gi/8.0 - alpha;
    double d=wigd(l,m,n,beta);
    double ph=-(alpha*m+gamma*n);
    Y2[idx]=make_float2((float)(d*cos(ph)),(float)(d*sin(ph)));
  } else if(blk<379){             // D2SJ: [j][286]
    int idx=(blk-365)*256+t; if(idx>=3432) return;
    int j=idx/286, s=idx%286;
    int l=0; while(B2OFFc[l+1]<=s) ++l;
    int r=s-B2OFFc[l]; int L=2*l+1;
    int mi=r/L, ni=r%L;
    double beta=PI_D*(2*j+1)/24.0;
    D2SJ[idx]=(float)((2*l+1)*wigd(l,mi-l,ni-l,beta));
  } else {                        // misc
    if(t<12){ double c=2.0*PI_D/12.0; WINT[t]=(float)(dhw(6,t)*c*c); }
    if(t<60){ double a=2.0*PI_D*t/60.0; E60[t]=make_float2((float)cos(a),(float)sin(a)); }
    if(t<20){ double a=2.0*PI_D*t/20.0; E20[t]=make_float2((float)cos(a),(float)sin(a)); }
    if(t<12){ double a=2.0*PI_D*t/12.0; E12[t]=make_float2((float)cos(a),(float)sin(a)); }
  }
}

// ---------------- front: per-b DFT + S2 analysis (XF in LDS), plus k1h ----------------
__global__ __launch_bounds__(256) void front_k(const float* __restrict__ x,
    const float* __restrict__ k1, const float2* __restrict__ E60,
    const float* __restrict__ A1, const float2* __restrict__ Y1,
    float2* __restrict__ XHAT, float2* __restrict__ K1H){
  __shared__ float xs[3600];
  __shared__ float2 E60s[60];
  __shared__ float2 XFs[1140];     // [j][mi], mi = m+9
  int blk=blockIdx.x, t=threadIdx.x;
  if(blk<128){
    if(t<60) E60s[t]=E60[t];
    {
      const float4* src=(const float4*)(x+blk*3600);
      float4* dst=(float4*)xs;
      for(int i=t;i<900;i+=256) dst[i]=src[i];
    }
    __syncthreads();
    for(int idx=t; idx<1140; idx+=256){
      int j=idx/19, mi=idx%19;
      int step=(mi<9)? mi+51 : mi-9;
      const float* xr=xs+j*60;
      float2 acc=make_float2(0.f,0.f);
      int k=0;
      for(int a=0;a<60;++a){
        float2 e=E60s[k]; float xv=xr[a];
        acc.x+=xv*e.x; acc.y-=xv*e.y;
        k+=step; if(k>=60)k-=60;
      }
      XFs[idx]=acc;
    }
    __syncthreads();
    for(int s=t; s<100; s+=256){
      int l=0; while((l+1)*(l+1)<=s) ++l;
      int m=s-l*l-l;
      const float2* xf=&XFs[m+9];
      float2 acc=make_float2(0.f,0.f);
      for(int j=0;j<60;++j){
        float a1=A1[j*NS1+s];
        float2 v=xf[j*19];
        acc.x+=a1*v.x; acc.y+=a1*v.y;
      }
      XHAT[blk*NS1+s]=acc;
    }
  } else {
    int idx=(blk-128)*256+t;
    if(idx<F1*NS1){
      int o=idx/NS1, s=idx%NS1;
      float2 acc=make_float2(0.f,0.f);
      for(int p=0;p<24;++p){
        float kv=k1[o*24+p];
        float2 y=Y1[p*NS1+s];
        acc.x+=kv*y.x; acc.y+=kv*y.y;
      }
      const float SC1f = 0.06123724356957945f;
      K1H[idx]=make_float2(acc.x*SC1f, acc.y*SC1f);
    }
  }
}

// fused1: wave-per-j barrier-free pipeline. XH2 layout: [b][s2][i]
__global__ __launch_bounds__(256,4) void fused1(
    const float2* __restrict__ XHAT, const float2* __restrict__ K1H,
    const float* __restrict__ D1SJ, const float* __restrict__ W3H,
    const float2* __restrict__ E20, const float* __restrict__ bias1,
    float2* __restrict__ XH2){
  const int b=blockIdx.x, o=blockIdx.y, t=threadIdx.x;
  const int ln=t&63, w=t>>6;
  __shared__ float2 zS[1330];
  __shared__ float2 TWE[580];        // [r=0..19][c=0..28], e^{i r (c-9) th}, stride 29
  __shared__ float2 regA[4][200];    // G[10][19] -> v(float[400]) -> Fq[61]
  __shared__ float2 regB[4][190];    // S[9][20]+T0(float[20]) -> U[20][6]
  __shared__ float2 acc2S[4][146];
  __shared__ short  fhS[146];

  for(int idx=t; idx<580; idx+=256){
    int r=idx/29, c=idx%29, n=c-9;
    int k=((r*n)%20+20)%20;
    TWE[idx]=E20[k];
  }
  for(int idx=t; idx<1330; idx+=256){
    int l=0; while(ZB10c[l+1]<=idx) ++l;
    int r=idx-ZB10c[l], L=2*l+1;
    int mi=r/L, ni=r%L;
    float2 xa=XHAT[b*NS1 + l*l+mi];
    float2 kb=K1H[o*NS1 + l*l+ni];
    zS[idx]=cmulc(xa,kb);
  }
  for(int idx=t; idx<146; idx+=256){
    int l,m,n; h_decode(idx,l,m,n);
    fhS[idx]=(short)((n==0)? m : 6+(n-1)*11+(m+5));
  }
  for(int idx=ln; idx<146; idx+=64) acc2S[w][idx]=make_float2(0.f,0.f);
  __syncthreads();

  const float bb1=bias1[o];
  float2* G  = regA[w];
  float*  vb = (float*)regA[w];
  float2* Fq = regA[w];
  float2* S  = regB[w];
  float*  T0 = (float*)(regB[w]+180);
  float2* U  = regB[w];
  float2* acc2 = acc2S[w];

  for(int jq=0;jq<5;++jq){
    const int j=jq*4+w;
    const float* Dg=D1SJ + j*1330;
    // A: Wigner-beta contraction, half-space (181 items)
    for(int idx=ln; idx<181; idx+=64){
      int m,n;
      if(idx<10){ m=0; n=idx; } else { int q=idx-10; m=q/19+1; n=q%19-9; }
      int an=n<0?-n:n;
      int l=m>an?m:an;
      int L=2*l+1;
      int zi=ZB10c[l]+(m+l)*L+(n+l);
      int m2=2*m+2;
      float2 a0=make_float2(0.f,0.f);
      for(; l<10; ++l){
        float2 zv=zS[zi]; float d=Dg[zi];
        a0.x+=zv.x*d; a0.y+=zv.y*d;
        zi += L*L + 2*L + m2; L += 2;
      }
      G[m*19+(n+9)]=a0;
    }
    WFENCE;
    // B: S_m(g)=2*sum_n G(m,n)e^{ing} (2-g batch) + ReT0(g)  (110 items)
    for(int idx=ln; idx<110; idx+=64){
      if(idx<90){
        int mb=idx/10+1, g=(idx%10)*2;
        const float2* Gr=&G[mb*19];
        const float2* E0=&TWE[g*29];
        const float2* E1=&TWE[(g+1)*29];
        float2 s0=make_float2(0.f,0.f), s1=s0;
        #pragma unroll
        for(int c=0;c<19;++c){
          float2 gv=Gr[c], e0=E0[c], e1=E1[c];
          s0.x+=gv.x*e0.x-gv.y*e0.y; s0.y+=gv.x*e0.y+gv.y*e0.x;
          s1.x+=gv.x*e1.x-gv.y*e1.y; s1.y+=gv.x*e1.y+gv.y*e1.x;
        }
        S[(mb-1)*20+g  ]=make_float2(2.f*s0.x,2.f*s0.y);
        S[(mb-1)*20+g+1]=make_float2(2.f*s1.x,2.f*s1.y);
      } else {
        int g=idx-90;
        const float2* Gr=&G[9];          // row m=0, n=0 at col 9
        const float2* Er=&TWE[g*29+9];
        float r=Gr[0].x;
        #pragma unroll
        for(int n=1;n<10;++n){ float2 gv=Gr[n], e=Er[n]; r+=2.f*(gv.x*e.x-gv.y*e.y); }
        T0[g]=r;
      }
    }
    WFENCE;
    // C: v(a,g)=T0+sum_m Re[S e^{ima}], bias, relu (4-g batch, 100 items)
    for(int idx=ln; idx<100; idx+=64){
      int a=idx/5, g4=(idx%5)*4;
      const float* T0p=&T0[g4];
      float v0=T0p[0]+bb1, v1=T0p[1]+bb1, v2=T0p[2]+bb1, v3=T0p[3]+bb1;
      const float2* Er=&TWE[a*29+9];
      const float2* Sc=&S[g4];
      #pragma unroll
      for(int m=1;m<10;++m){
        float2 e=Er[m];
        const float2* Sp=Sc+(m-1)*20;
        float2 s0=Sp[0],s1=Sp[1],s2=Sp[2],s3=Sp[3];
        v0+=s0.x*e.x-s0.y*e.y; v1+=s1.x*e.x-s1.y*e.y;
        v2+=s2.x*e.x-s2.y*e.y; v3+=s3.x*e.x-s3.y*e.y;
      }
      float* vp=&vb[a*20+g4];
      vp[0]=v0>0.f?v0:0.f; vp[1]=v1>0.f?v1:0.f;
      vp[2]=v2>0.f?v2:0.f; vp[3]=v3>0.f?v3:0.f;
    }
    WFENCE;
    // D: U(a,nu)=sum_g v e^{-i nu g} (row (20-nu)%20), 2-nu batch (60 items)
    for(int idx=ln; idx<60; idx+=64){
      int a=idx/3, np=idx%3;
      int nu0=2*np, nu1=2*np+1;
      int r0=(20-nu0)%20, r1=19-2*np;
      const float* vp=&vb[a*20];
      const float2* E0=&TWE[r0*29+9];
      const float2* E1=&TWE[r1*29+9];
      float2 u0=make_float2(0.f,0.f), u1=u0;
      #pragma unroll
      for(int g=0;g<20;++g){
        float xv=vp[g]; float2 e0=E0[g], e1=E1[g];
        u0.x+=xv*e0.x; u0.y+=xv*e0.y;
        u1.x+=xv*e1.x; u1.y+=xv*e1.y;
      }
      U[a*6+nu0]=u0; U[a*6+nu1]=u1;
    }
    WFENCE;
    // E: Fq(mu,nu)=sum_a U e^{-i mu a} (row (-mu)%20), 61 half items
    for(int idx=ln; idx<61; idx+=64){
      int mu,nu;
      if(idx<6){ mu=idx; nu=0; } else { int q=idx-6; nu=q/11+1; mu=q%11-5; }
      int rm=(20-((mu+20)%20))%20;
      const float2* Er=&TWE[rm*29+9];
      const float2* Up=&U[nu];
      float2 f=make_float2(0.f,0.f);
      #pragma unroll
      for(int a=0;a<20;++a){
        float2 u=Up[a*6], e=Er[a];
        f.x+=u.x*e.x-u.y*e.y; f.y+=u.x*e.y+u.y*e.x;
      }
      Fq[idx]=f;
    }
    WFENCE;
    // F: accumulate half-s2 with W3H
    {
      const float* W3r=W3H + j*NH2;
      for(int idx=ln; idx<146; idx+=64){
        float wv=W3r[idx];
        float2 f=Fq[fhS[idx]];
        acc2[idx].x+=wv*f.x; acc2[idx].y+=wv*f.y;
      }
    }
    WFENCE;
  }
  __syncthreads();
  // merge 4 waves + expand half -> full XH2 by conjugation
  for(int h=t; h<146; h+=256){
    int l,m,n; h_decode(h,l,m,n);
    int L=2*l+1;
    int s2 =B2OFFc[l]+(m+l)*L+(n+l);
    int s2p=B2OFFc[l]+(l-m)*L+(l-n);
    float2 a0=acc2S[0][h], a1=acc2S[1][h], a2=acc2S[2][h], a3=acc2S[3][h];
    float2 a=make_float2(a0.x+a1.x+a2.x+a3.x, a0.y+a1.y+a2.y+a3.y);
    float sg=((m+n)&1)? -1.f : 1.f;
    XH2[(b*286+s2 )*F1+o]=a;
    XH2[(b*286+s2p)*F1+o]=make_float2(sg*a.x, -sg*a.y);
  }
}

// K2H layout: [o][s2][i] — Hermitian half computed, other half by conjugation
__global__ void k2h_k(const float* __restrict__ k2, const float2* __restrict__ Y2,
                      float2* __restrict__ K2H){
  int idx=blockIdx.x*blockDim.x+threadIdx.x;
  if(idx>=NH2*F1*F2) return;
  int o=idx/(NH2*F1); int r=idx%(NH2*F1); int h=r/F1, i=r%F1;
  int l,m,n; h_decode(h,l,m,n);
  int L=2*l+1;
  int s2 =B2OFFc[l]+(m+l)*L+(n+l);
  int s2p=B2OFFc[l]+(l-m)*L+(l-n);
  float2 acc=make_float2(0.f,0.f);
  const float* kr=k2+(i*F2+o)*192;
  const float2* yr=Y2+s2;
  for(int p=0;p<192;++p){
    float kv=kr[p];
    float2 y=yr[p*NS2];
    acc.x+=kv*y.x; acc.y+=kv*y.y;
  }
  const float SC2f = 0.034722222222222224f;
  acc.x*=SC2f; acc.y*=SC2f;
  K2H[(o*286+s2)*F1+i]=acc;
  float sg=((m+n)&1)?-1.f:1.f;
  K2H[(o*286+s2p)*F1+i]=make_float2(sg*acc.x,-sg*acc.y);
}

// fused2: cooperative z2 build, then wave-per-j barrier-free synthesis+integrate
__global__ __launch_bounds__(256,3) void fused2(
    const float2* __restrict__ XH2, const float2* __restrict__ K2H,
    const float* __restrict__ D2SJ, const float* __restrict__ WINT,
    const float2* __restrict__ E12, const float* __restrict__ bias2,
    float* __restrict__ FEAT){
  const int b=blockIdx.x, o=blockIdx.y, t=threadIdx.x;
  const int ln=t&63, w=t>>6;
  __shared__ __align__(16) float2 Xs[2420];
  __shared__ __align__(16) float2 Ks[2420];
  __shared__ float2 zpS[1144];
  __shared__ float2 z2S[286];
  __shared__ float  redS[256];
  float2* alias=(float2*)Xs;       // reused after z-build
  float2* TW12=alias;              // [12][17]: e^{i r (c-5) th12}, stride 17

  const int gb[4]={0,84,165,286};
  const int hb[4]={0,44,85,146};
  for(int grp=0; grp<3; ++grp){
    int row0=gb[grp], rows=gb[grp+1]-row0;
    {
      int cnt4=rows*10;
      const float4* xsrc=(const float4*)(XH2+(size_t)(b*286+row0)*F1);
      const float4* ksrc=(const float4*)(K2H+(size_t)(o*286+row0)*F1);
      float4* xd=(float4*)Xs; float4* kd=(float4*)Ks;
      for(int i=t;i<cnt4;i+=256){ xd[i]=xsrc[i]; kd[i]=ksrc[i]; }
    }
    __syncthreads();
    int nh=hb[grp+1]-hb[grp];
    for(int idx=t; idx<4*nh; idx+=256){
      int hl=idx>>2, iq=idx&3;
      int h=hb[grp]+hl;
      int l,m,n; h_decode(h,l,m,n);
      int L=2*l+1;
      int s2=B2OFFc[l]+(m+l)*L+(n+l);
      int xr0=(B2OFFc[l]-row0)+(m+l)*L;
      int kr0=(B2OFFc[l]-row0)+(n+l)*L;
      float2 acc=make_float2(0.f,0.f);
      for(int k=0;k<L;++k){
        const float2* xp=Xs+(xr0+k)*F1+iq*5;
        const float2* kp=Ks+(kr0+k)*F1+iq*5;
        #pragma unroll
        for(int i=0;i<5;++i){
          float2 xa=xp[i], kb=kp[i];
          acc.x += xa.x*kb.x + xa.y*kb.y;
          acc.y += xa.y*kb.x - xa.x*kb.y;
        }
      }
      zpS[iq*286+s2]=acc;
    }
    __syncthreads();
  }
  // merge partials + Hermitian fill
  for(int idx=t; idx<146; idx+=256){
    int l,m,n; h_decode(idx,l,m,n);
    int L=2*l+1;
    int s2 =B2OFFc[l]+(m+l)*L+(n+l);
    int s2p=B2OFFc[l]+(l-m)*L+(l-n);
    float2 a;
    a.x=zpS[0*286+s2].x+zpS[1*286+s2].x+zpS[2*286+s2].x+zpS[3*286+s2].x;
    a.y=zpS[0*286+s2].y+zpS[1*286+s2].y+zpS[2*286+s2].y+zpS[3*286+s2].y;
    z2S[s2]=a;
    float sg=((m+n)&1)?-1.f:1.f;
    z2S[s2p]=make_float2(sg*a.x,-sg*a.y);
  }
  __syncthreads();
  for(int idx=t; idx<204; idx+=256){
    int r=idx/17, c=idx%17, n=c-5;
    int k=((r*n)%12+12)%12;
    TW12[idx]=E12[k];
  }
  __syncthreads();

  float2* G2=alias+204+w*132;
  float2* S2=G2+66;
  float*  T02=(float*)(S2+60);
  float personal=0.f;
  const float b2v=bias2[o];
  for(int jq=0;jq<3;++jq){
    const int j=jq*4+w;
    const float* Dg=D2SJ + j*286;
    // A2: 61 half items
    for(int idx=ln; idx<61; idx+=64){
      int m,n;
      if(idx<6){m=0;n=idx;} else {int q=idx-6;m=q/11+1;n=q%11-5;}
      int an=n<0?-n:n; int l=m>an?m:an; int L=2*l+1;
      int zi=B2OFFc[l]+(m+l)*L+(n+l); int m2=2*m+2;
      float2 a0=make_float2(0.f,0.f);
      for(;l<6;++l){
        float2 zv=z2S[zi]; float d=Dg[zi];
        a0.x+=zv.x*d; a0.y+=zv.y*d;
        zi+=L*L+2*L+m2; L+=2;
      }
      G2[m*11+(n+5)]=a0;
    }
    WFENCE;
    // B2: 42 items (30 S-pairs + 12 T0)
    for(int idx=ln; idx<42; idx+=64){
      if(idx<30){
        int m=idx/6+1, g=(idx%6)*2;
        const float2* Gr=&G2[m*11];
        const float2* E0=&TW12[g*17];
        const float2* E1=&TW12[(g+1)*17];
        float2 s0=make_float2(0.f,0.f), s1=s0;
        #pragma unroll
        for(int c=0;c<11;++c){
          float2 gv=Gr[c], e0=E0[c], e1=E1[c];
          s0.x+=gv.x*e0.x-gv.y*e0.y; s0.y+=gv.x*e0.y+gv.y*e0.x;
          s1.x+=gv.x*e1.x-gv.y*e1.y; s1.y+=gv.x*e1.y+gv.y*e1.x;
        }
        S2[(m-1)*12+g  ]=make_float2(2.f*s0.x,2.f*s0.y);
        S2[(m-1)*12+g+1]=make_float2(2.f*s1.x,2.f*s1.y);
      } else {
        int g=idx-30;
        const float2* Gr=&G2[5];
        const float2* Er=&TW12[g*17+5];
        float r=Gr[0].x;
        #pragma unroll
        for(int n=1;n<6;++n){ float2 gv=Gr[n], e=Er[n]; r+=2.f*(gv.x*e.x-gv.y*e.y); }
        T02[g]=r;
      }
    }
    WFENCE;
    // C2: 36 items, 4-g batch, fused relu+integrate
    {
      float wj=WINT[j];
      for(int idx=ln; idx<36; idx+=64){
        int a=idx/3, g4=(idx%3)*4;
        const float* T0p=&T02[g4];
        float v0=T0p[0]+b2v,v1=T0p[1]+b2v,v2=T0p[2]+b2v,v3=T0p[3]+b2v;
        const float2* Er=&TW12[a*17+5];
        const float2* Sc=&S2[g4];
        #pragma unroll
        for(int m=1;m<6;++m){
          float2 e=Er[m];
          const float2* Sp=Sc+(m-1)*12;
          float2 s0=Sp[0],s1=Sp[1],s2=Sp[2],s3=Sp[3];
          v0+=s0.x*e.x-s0.y*e.y; v1+=s1.x*e.x-s1.y*e.y;
          v2+=s2.x*e.x-s2.y*e.y; v3+=s3.x*e.x-s3.y*e.y;
        }
        personal += wj*((v0>0.f?v0:0.f)+(v1>0.f?v1:0.f)+(v2>0.f?v2:0.f)+(v3>0.f?v3:0.f));
      }
    }
    WFENCE;
  }
  redS[t]=personal;
  __syncthreads();
  for(int s=128;s>0;s>>=1){
    if(t<s) redS[t]+=redS[t+s];
    __syncthreads();
  }
  if(t==0) FEAT[b*F2+o]=redS[0];
}

__global__ void head_k(const float* __restrict__ FEAT, const float* __restrict__ w_out,
                       const float* __restrict__ b_lin, float* __restrict__ out){
  int idx=blockIdx.x*blockDim.x+threadIdx.x;
  if(idx>=BATCH*FOUT) return;
  int b=idx/FOUT, q=idx%FOUT;
  float acc=b_lin[q];
  for(int f=0;f<F2;++f) acc += FEAT[b*F2+f]*w_out[q*F2+f];
  out[idx]=acc;
}

extern "C" void kernel_launch(void* const* d_in, const int* in_sizes, int n_in,
                              void* d_out, int out_size, void* d_ws, size_t ws_size,
                              hipStream_t stream) {
  const float* x    =(const float*)d_in[0];
  const float* k1   =(const float*)d_in[1];
  const float* bias1=(const float*)d_in[2];
  const float* k2   =(const float*)d_in[3];
  const float* bias2=(const float*)d_in[4];
  const float* w_out=(const float*)d_in[5];
  const float* b_lin=(const float*)d_in[6];
  float* out=(float*)d_out;

  char* ws=(char*)d_ws;
  float*  A1  =(float* )(ws+0);        //  6000 f       24000
  float2* Y1  =(float2*)(ws+24000);    //  2400 c       19200
  float*  D1SJ=(float* )(ws+43200);    //  26600 f      106400
  float*  W3H =(float* )(ws+149600);   //  20*146 f     11680
  float2* Y2  =(float2*)(ws+161280);   //  192*286 c    439296
  float*  D2SJ=(float* )(ws+600576);   //  3432 f       13728
  float*  WINT=(float* )(ws+614304);   //  12 f         48
  float2* E60 =(float2*)(ws+614352);   //  60 c         480
  float2* E20 =(float2*)(ws+614832);   //  20 c         160
  float2* E12 =(float2*)(ws+614992);   //  12 c         96 (+16 pad)
  float2* XHAT=(float2*)(ws+615104);   //  [b][100] c   102400
  float2* K1H =(float2*)(ws+717504);   //  [o][100] c   16000
  float2* XH2 =(float2*)(ws+733504);   //  [b][286][20] 5857280
  float2* K2H =(float2*)(ws+6590784);  //  [o][286][20] 1830400
  float*  FEAT=(float* )(ws+8421184);  //  128*40 f     20480  -> 8441664 total

  (void)in_sizes; (void)n_in; (void)out_size; (void)ws_size;

  gen_all<<<380,256,0,stream>>>(A1,Y1,D1SJ,W3H,Y2,D2SJ,WINT,E60,E20,E12);
  front_k<<<136,256,0,stream>>>(x,k1,E60,A1,Y1,XHAT,K1H);
  dim3 g1(BATCH,F1);
  fused1<<<g1,256,0,stream>>>(XHAT,K1H,D1SJ,W3H,E20,bias1,XH2);
  k2h_k<<<(NH2*F1*F2+255)/256,256,0,stream>>>(k2,Y2,K2H);
  dim3 g2(BATCH,F2);
  fused2<<<g2,256,0,stream>>>(XH2,K2H,D2SJ,WINT,E12,bias2,FEAT);
  head_k<<<(BATCH*FOUT+255)/256,256,0,stream>>>(FEAT,w_out,b_lin,out);
}

// Round 6
// 333.729 us; speedup vs baseline: 5.3380x; 1.0804x over previous
//
#include <hip/hip_runtime.h>
#include <math.h>

#define PI_D 3.14159265358979323846

#define BATCH 128
#define F1 20
#define F2 40
#define FOUT 10
#define NS1 100   // sum_{l<10} (2l+1)
#define NS2 286   // sum_{l<6} (2l+1)^2
#define NH2 146   // Hermitian half count of NS2

__constant__ int ZB10c[11] = {0,1,10,35,84,165,286,455,680,969,1330};
__constant__ int B2OFFc[7] = {0,1,10,35,84,165,286};
__constant__ int HOFFc[7]  = {0,1,6,19,44,85,146};
// E8c[q] = exp(-2*pi*i*q/8)
__constant__ float2 E8c[8] = {
  { 1.f, 0.f}, { 0.70710678118654752f,-0.70710678118654752f},
  { 0.f,-1.f}, {-0.70710678118654752f,-0.70710678118654752f},
  {-1.f, 0.f}, {-0.70710678118654752f, 0.70710678118654752f},
  { 0.f, 1.f}, { 0.70710678118654752f, 0.70710678118654752f}};

// wave-synchronous phase fence
#define WFENCE do{ __builtin_amdgcn_sched_barrier(0); \
  asm volatile("s_waitcnt lgkmcnt(0)" ::: "memory"); \
  __builtin_amdgcn_sched_barrier(0); }while(0)

// half-space H = { (m,n): n>0 } U { (m,n): n==0 && m>=0 }
__device__ inline void h_decode(int h, int& l, int& m, int& n){
  l=0; while(HOFFc[l+1]<=h) ++l;
  int r=h-HOFFc[l], L=2*l+1;
  if(r<l+1){ n=0; m=r; }
  else { int q=r-(l+1); n=q/L+1; m=q%L-l; }
}

// ---------------- double-precision table generation helpers ----------------
__device__ inline double ipow_d(double x, int n){ double r=1.0; for(int i=0;i<n;++i) r*=x; return r; }
__device__ inline double dfact(int n){ double r=1.0; for(int i=2;i<=n;++i) r*=(double)i; return r; }

__device__ double wigd(int l, int mp, int m, double beta){
  double cb=cos(0.5*beta), sb=sin(0.5*beta);
  double pref=sqrt(dfact(l+mp)*dfact(l-mp)*dfact(l+m)*dfact(l-m));
  int s0 = (m-mp>0) ? (m-mp) : 0;
  int s1 = (l+m < l-mp) ? (l+m) : (l-mp);
  double acc=0.0;
  for(int s=s0;s<=s1;++s){
    double den=dfact(l+m-s)*dfact(s)*dfact(mp-m+s)*dfact(l-mp-s);
    double t=ipow_d(cb,2*l+m-mp-2*s)*ipow_d(sb,mp-m+2*s)/den;
    acc += ((mp-m+s)&1)? -t : t;
  }
  return pref*acc;
}

__device__ double dhw(int b, int j){
  double beta=PI_D*(2*j+1)/(4.0*b);
  double s=0.0;
  for(int k=0;k<b;++k) s += sin((2*k+1)*beta)/(2*k+1);
  return (2.0/b)*sin(beta)*s;
}

__device__ inline float2 cmulc(float2 a, float2 b){ // a * conj(b)
  return make_float2(a.x*b.x + a.y*b.y, a.y*b.x - a.x*b.y);
}

// ---------------- single merged table-generation kernel ----------------
// blocks: 0-23 A1 | 24-127 D1SJ | 128-139 W3H | 140-153 D2SJ | 154-157 D3_2 | 158-159 D3_1 | 160 misc
__global__ void gen_all(float* A1, float* D1SJ, float* W3H, float* D2SJ,
                        float* D3_2, float* D3_1, float* WINT,
                        float2* E60, float2* E20, float2* E12){
  int blk=blockIdx.x, t=threadIdx.x;
  if(blk<24){                     // A1: [j][s1], 60x100
    int idx=blk*256+t; if(idx>=6000) return;
    int j=idx/NS1, s=idx%NS1;
    int l=0; while((l+1)*(l+1)<=s) ++l;
    int m=s-l*l-l;
    double beta=PI_D*(2*j+1)/120.0;
    A1[idx]=(float)(wigd(l,m,0,beta)*dhw(30,j)*(2.0*PI_D/60.0));
  } else if(blk<128){             // D1SJ: [j][1330]
    int idx=(blk-24)*256+t; if(idx>=26600) return;
    int j=idx/1330, s=idx%1330;
    int l=0; while(ZB10c[l+1]<=s) ++l;
    int r=s-ZB10c[l]; int L=2*l+1;
    int mi=r/L, ni=r%L;
    double beta=PI_D*(2*j+1)/40.0;
    D1SJ[idx]=(float)((2*l+1)*wigd(l,mi-l,ni-l,beta));
  } else if(blk<140){             // W3H: [j][146]
    int idx=(blk-128)*256+t; if(idx>=20*NH2) return;
    int j=idx/NH2, h=idx%NH2;
    int l,m,n; h_decode(h,l,m,n);
    double beta=PI_D*(2*j+1)/40.0;
    double c=2.0*PI_D/20.0;
    W3H[idx]=(float)(wigd(l,m,n,beta)*dhw(10,j)*c*c);
  } else if(blk<154){             // D2SJ: [j][286]
    int idx=(blk-140)*256+t; if(idx>=3432) return;
    int j=idx/286, s=idx%286;
    int l=0; while(B2OFFc[l+1]<=s) ++l;
    int r=s-B2OFFc[l]; int L=2*l+1;
    int mi=r/L, ni=r%L;
    double beta=PI_D*(2*j+1)/24.0;
    D2SJ[idx]=(float)((2*l+1)*wigd(l,mi-l,ni-l,beta));
  } else if(blk<158){             // D3_2: [bi][286] wigner at the 3 grid betas
    int idx=(blk-154)*256+t; if(idx>=3*286) return;
    int bi=idx/286, s=idx%286;
    int l=0; while(B2OFFc[l+1]<=s) ++l;
    int r=s-B2OFFc[l]; int L=2*l+1;
    int mi=r/L, ni=r%L;
    double beta=(bi+1)*(PI_D/8.0)/3.0;
    D3_2[idx]=(float)wigd(l,mi-l,ni-l,beta);
  } else if(blk<160){             // D3_1: [bi][100]
    int idx=(blk-158)*256+t; if(idx>=3*100) return;
    int bi=idx/100, s=idx%100;
    int l=0; while((l+1)*(l+1)<=s) ++l;
    int m=s-l*l-l;
    double beta=(bi+1)*(PI_D/8.0)/3.0;
    D3_1[idx]=(float)wigd(l,m,0,beta);
  } else {                        // misc
    if(t<12){ double c=2.0*PI_D/12.0; WINT[t]=(float)(dhw(6,t)*c*c); }
    if(t<60){ double a=2.0*PI_D*t/60.0; E60[t]=make_float2((float)cos(a),(float)sin(a)); }
    if(t<20){ double a=2.0*PI_D*t/20.0; E20[t]=make_float2((float)cos(a),(float)sin(a)); }
    if(t<12){ double a=2.0*PI_D*t/12.0; E12[t]=make_float2((float)cos(a),(float)sin(a)); }
  }
}

// ---------------- front: per-b DFT + S2 analysis, plus k1h via E8 phases ----------------
__global__ __launch_bounds__(256) void front_k(const float* __restrict__ x,
    const float* __restrict__ k1, const float2* __restrict__ E60,
    const float* __restrict__ A1, const float* __restrict__ D3_1,
    float2* __restrict__ XHAT, float2* __restrict__ K1H){
  int blk=blockIdx.x, t=threadIdx.x;
  if(blk<128){
    __shared__ float xs[3600];
    __shared__ float2 E60s[60];
    __shared__ float2 XFs[1140];     // [j][mi], mi = m+9
    if(t<60) E60s[t]=E60[t];
    {
      const float4* src=(const float4*)(x+blk*3600);
      float4* dst=(float4*)xs;
      for(int i=t;i<900;i+=256) dst[i]=src[i];
    }
    __syncthreads();
    for(int idx=t; idx<1140; idx+=256){
      int j=idx/19, mi=idx%19;
      int step=(mi<9)? mi+51 : mi-9;
      const float* xr=xs+j*60;
      float2 acc=make_float2(0.f,0.f);
      int k=0;
      for(int a=0;a<60;++a){
        float2 e=E60s[k]; float xv=xr[a];
        acc.x+=xv*e.x; acc.y-=xv*e.y;
        k+=step; if(k>=60)k-=60;
      }
      XFs[idx]=acc;
    }
    __syncthreads();
    for(int s=t; s<100; s+=256){
      int l=0; while((l+1)*(l+1)<=s) ++l;
      int m=s-l*l-l;
      const float2* xf=&XFs[m+9];
      float2 acc=make_float2(0.f,0.f);
      for(int j=0;j<60;++j){
        float a1=A1[j*NS1+s];
        float2 v=xf[j*19];
        acc.x+=a1*v.x; acc.y+=a1*v.y;
      }
      XHAT[blk*NS1+s]=acc;
    }
  } else {
    __shared__ float2 E8s[8];
    if(t<8) E8s[t]=E8c[t];
    __syncthreads();
    int idx=(blk-128)*256+t;
    if(idx<F1*NS1){
      int o=idx/NS1, s=idx%NS1;
      int l=0; while((l+1)*(l+1)<=s) ++l;
      int m=s-l*l-l;
      int mm=m&7;
      float2 acc=make_float2(0.f,0.f);
      for(int bi=0;bi<3;++bi){
        float2 sum=make_float2(0.f,0.f);
        int q=0;
        #pragma unroll
        for(int ai=0;ai<8;++ai){
          float kv=k1[o*24+bi*8+ai];
          float2 e=E8s[q];
          sum.x+=kv*e.x; sum.y+=kv*e.y;
          q=(q+mm)&7;
        }
        float dv=D3_1[bi*100+s];
        acc.x+=dv*sum.x; acc.y+=dv*sum.y;
      }
      const float SC1f = 0.06123724356957945f;
      K1H[idx]=make_float2(acc.x*SC1f, acc.y*SC1f);
    }
  }
}

// fused1: wave-per-j barrier-free pipeline, register F-accumulators.
// XH2 layout: [b][s2][i]
__global__ __launch_bounds__(256,4) void fused1(
    const float2* __restrict__ XHAT, const float2* __restrict__ K1H,
    const float* __restrict__ D1SJ, const float* __restrict__ W3H,
    const float2* __restrict__ E20, const float* __restrict__ bias1,
    float2* __restrict__ XH2){
  const int b=blockIdx.x, o=blockIdx.y, t=threadIdx.x;
  const int ln=t&63, w=t>>6;
  __shared__ float2 zS[1330];
  __shared__ float2 TWE2[400];       // [r][k] = e^{i r k th}, 20x20
  __shared__ float2 TWT[380];        // [n9][g] = e^{i (n9-9) g th}, 19x20
  __shared__ float2 regA[4][200];    // G[10][19] -> v(float[400]) -> Fq[61]
  __shared__ float2 regB[4][190];    // S[9][20]+T0(float[20]) -> U_T[6][20] -> final acc
  __shared__ short  fhS[146];

  for(int idx=t; idx<400; idx+=256){
    int r=idx/20, c=idx%20;
    TWE2[idx]=E20[(r*c)%20];
  }
  for(int idx=t; idx<380; idx+=256){
    int n9=idx/20, g=idx%20;
    int k=(((n9-9)*g)%20+20)%20;
    TWT[idx]=E20[k];
  }
  for(int idx=t; idx<1330; idx+=256){
    int l=0; while(ZB10c[l+1]<=idx) ++l;
    int r=idx-ZB10c[l], L=2*l+1;
    int mi=r/L, ni=r%L;
    float2 xa=XHAT[b*NS1 + l*l+mi];
    float2 kb=K1H[o*NS1 + l*l+ni];
    zS[idx]=cmulc(xa,kb);
  }
  for(int idx=t; idx<146; idx+=256){
    int l,m,n; h_decode(idx,l,m,n);
    fhS[idx]=(short)((n==0)? m : 6+(n-1)*11+(m+5));
  }
  __syncthreads();

  const float bb1=bias1[o];
  float2* G  = regA[w];
  float*  vb = (float*)regA[w];
  float2* Fq = regA[w];
  float2* S  = regB[w];
  float*  T0 = (float*)(regB[w]+180);
  float2* U_T= regB[w];
  float2 fa0=make_float2(0.f,0.f), fa1=fa0, fa2=fa0;

  for(int jq=0;jq<5;++jq){
    const int j=jq*4+w;
    const float* Dg=D1SJ + j*1330;
    // A: Wigner-beta contraction, half-space (181 items, 3 passes)
    for(int idx=ln; idx<181; idx+=64){
      int m,n;
      if(idx<10){ m=0; n=idx; } else { int q=idx-10; m=q/19+1; n=q%19-9; }
      int an=n<0?-n:n;
      int l=m>an?m:an;
      int L=2*l+1;
      int zi=ZB10c[l]+(m+l)*L+(n+l);
      int m2=2*m+2;
      float2 a0=make_float2(0.f,0.f);
      for(; l<10; ++l){
        float2 zv=zS[zi]; float d=Dg[zi];
        a0.x+=zv.x*d; a0.y+=zv.y*d;
        zi += L*L + 2*L + m2; L += 2;
      }
      G[m*19+(n+9)]=a0;
    }
    WFENCE;
    // B: S_m(g4)=2*sum_n G(m,n)e^{ing} (45 items) + T0 quads (5 items), single pass
    if(ln<45){
      int mb=ln/5+1, g0=(ln%5)*4;
      const float2* Gr=&G[mb*19];
      float2 s0=make_float2(0.f,0.f), s1=s0, s2=s0, s3=s0;
      #pragma unroll
      for(int c=0;c<19;++c){
        float2 gv=Gr[c];
        const float2* tw=&TWT[c*20+g0];
        float2 e0=tw[0],e1=tw[1],e2=tw[2],e3=tw[3];
        s0.x+=gv.x*e0.x-gv.y*e0.y; s0.y+=gv.x*e0.y+gv.y*e0.x;
        s1.x+=gv.x*e1.x-gv.y*e1.y; s1.y+=gv.x*e1.y+gv.y*e1.x;
        s2.x+=gv.x*e2.x-gv.y*e2.y; s2.y+=gv.x*e2.y+gv.y*e2.x;
        s3.x+=gv.x*e3.x-gv.y*e3.y; s3.y+=gv.x*e3.y+gv.y*e3.x;
      }
      float2* Sp=&S[(mb-1)*20+g0];
      Sp[0]=make_float2(2.f*s0.x,2.f*s0.y);
      Sp[1]=make_float2(2.f*s1.x,2.f*s1.y);
      Sp[2]=make_float2(2.f*s2.x,2.f*s2.y);
      Sp[3]=make_float2(2.f*s3.x,2.f*s3.y);
    } else if(ln<50){
      int g0=(ln-45)*4;
      float r0=G[9].x, r1=r0, r2=r0, r3=r0;   // n=0 term
      #pragma unroll
      for(int n=1;n<10;++n){
        float2 gv=G[9+n];
        const float2* tw=&TWT[(n+9)*20+g0];
        float2 e0=tw[0],e1=tw[1],e2=tw[2],e3=tw[3];
        r0+=2.f*(gv.x*e0.x-gv.y*e0.y);
        r1+=2.f*(gv.x*e1.x-gv.y*e1.y);
        r2+=2.f*(gv.x*e2.x-gv.y*e2.y);
        r3+=2.f*(gv.x*e3.x-gv.y*e3.y);
      }
      T0[g0]=r0; T0[g0+1]=r1; T0[g0+2]=r2; T0[g0+3]=r3;
    }
    WFENCE;
    // C: v(a,g)=T0+sum_m Re[S e^{ima}], bias, relu; 2-a x 4-g batch (50 items)
    if(ln<50){
      int ap=ln/5, g0=(ln%5)*4;
      int a0=2*ap, a1=a0+1;
      float t0=T0[g0]+bb1, t1=T0[g0+1]+bb1, t2=T0[g0+2]+bb1, t3=T0[g0+3]+bb1;
      float v00=t0,v01=t1,v02=t2,v03=t3;
      float v10=t0,v11=t1,v12=t2,v13=t3;
      const float2* E0=&TWE2[a0*20];
      const float2* E1=&TWE2[a1*20];
      #pragma unroll
      for(int m=1;m<10;++m){
        float2 e0=E0[m], e1=E1[m];
        const float2* Sp=&S[(m-1)*20+g0];
        float2 s0=Sp[0],s1=Sp[1],s2=Sp[2],s3=Sp[3];
        v00+=s0.x*e0.x-s0.y*e0.y; v01+=s1.x*e0.x-s1.y*e0.y;
        v02+=s2.x*e0.x-s2.y*e0.y; v03+=s3.x*e0.x-s3.y*e0.y;
        v10+=s0.x*e1.x-s0.y*e1.y; v11+=s1.x*e1.x-s1.y*e1.y;
        v12+=s2.x*e1.x-s2.y*e1.y; v13+=s3.x*e1.x-s3.y*e1.y;
      }
      float* vp0=&vb[a0*20+g0];
      float* vp1=&vb[a1*20+g0];
      vp0[0]=v00>0.f?v00:0.f; vp0[1]=v01>0.f?v01:0.f;
      vp0[2]=v02>0.f?v02:0.f; vp0[3]=v03>0.f?v03:0.f;
      vp1[0]=v10>0.f?v10:0.f; vp1[1]=v11>0.f?v11:0.f;
      vp1[2]=v12>0.f?v12:0.f; vp1[3]=v13>0.f?v13:0.f;
    }
    WFENCE;
    // D: U_T[nu][a]=sum_g v(a,g) e^{-i nu g} via rows (20-nu)%20; 2-nu batch (60 items)
    if(ln<60){
      int a=ln/3, np=ln%3;
      int nu0=2*np, nu1=2*np+1;
      int r0=(np==0)?0:(20-2*np);
      int r1=19-2*np;
      const float* vp=&vb[a*20];
      const float2* T0r=&TWE2[r0*20];
      const float2* T1r=&TWE2[r1*20];
      float2 u0=make_float2(0.f,0.f), u1=u0;
      #pragma unroll
      for(int g=0;g<20;++g){
        float xv=vp[g];
        float2 e0=T0r[g], e1=T1r[g];
        u0.x+=xv*e0.x; u0.y+=xv*e0.y;
        u1.x+=xv*e1.x; u1.y+=xv*e1.y;
      }
      U_T[nu0*20+a]=u0; U_T[nu1*20+a]=u1;
    }
    WFENCE;
    // E: Fq(mu,nu)=sum_a U_T[nu][a] e^{-i mu a}; 61 half items
    if(ln<61){
      int mu,nu;
      if(ln<6){ mu=ln; nu=0; } else { int q=ln-6; nu=q/11+1; mu=q%11-5; }
      int mm=(mu+20)%20;
      int rm=(20-mm)%20;
      const float2* Ur=&U_T[nu*20];
      const float2* Er=&TWE2[rm*20];
      float2 f=make_float2(0.f,0.f);
      #pragma unroll
      for(int a=0;a<20;++a){
        float2 u=Ur[a], e=Er[a];
        f.x+=u.x*e.x-u.y*e.y; f.y+=u.x*e.y+u.y*e.x;
      }
      Fq[ln]=f;
    }
    WFENCE;
    // F: accumulate half-s2 with W3H into registers
    {
      const float* W3r=W3H + j*NH2;
      float wv; float2 f;
      wv=W3r[ln];     f=Fq[fhS[ln]];     fa0.x+=wv*f.x; fa0.y+=wv*f.y;
      wv=W3r[64+ln];  f=Fq[fhS[64+ln]];  fa1.x+=wv*f.x; fa1.y+=wv*f.y;
      if(ln<18){ wv=W3r[128+ln]; f=Fq[fhS[128+ln]]; fa2.x+=wv*f.x; fa2.y+=wv*f.y; }
    }
    WFENCE;
  }
  // spill register accumulators, merge 4 waves, expand half->full by conjugation
  regB[w][ln]=fa0; regB[w][64+ln]=fa1;
  if(ln<18) regB[w][128+ln]=fa2;
  __syncthreads();
  for(int h=t; h<146; h+=256){
    int l,m,n; h_decode(h,l,m,n);
    int L=2*l+1;
    int s2 =B2OFFc[l]+(m+l)*L+(n+l);
    int s2p=B2OFFc[l]+(l-m)*L+(l-n);
    float2 a0=regB[0][h], a1=regB[1][h], a2=regB[2][h], a3=regB[3][h];
    float2 a=make_float2(a0.x+a1.x+a2.x+a3.x, a0.y+a1.y+a2.y+a3.y);
    float sg=((m+n)&1)? -1.f : 1.f;
    XH2[(b*286+s2 )*F1+o]=a;
    XH2[(b*286+s2p)*F1+o]=make_float2(sg*a.x, -sg*a.y);
  }
}

// K2H layout: [o][s2][i] — Hermitian half via D3_2 + E8 phases, conj-filled
__global__ void k2h_k(const float* __restrict__ k2, const float* __restrict__ D3_2,
                      float2* __restrict__ K2H){
  __shared__ float2 E8s[8];
  if(threadIdx.x<8) E8s[threadIdx.x]=E8c[threadIdx.x];
  __syncthreads();
  int idx=blockIdx.x*blockDim.x+threadIdx.x;
  if(idx>=NH2*F1*F2) return;
  int o=idx/(NH2*F1); int r=idx%(NH2*F1); int h=r/F1, i=r%F1;
  int l,m,n; h_decode(h,l,m,n);
  int L=2*l+1;
  int s2 =B2OFFc[l]+(m+l)*L+(n+l);
  int s2p=B2OFFc[l]+(l-m)*L+(l-n);
  int dmn=(m-n)&7, nn=n&7;
  const float4* kr4=(const float4*)(k2+(size_t)(i*F2+o)*192);
  float2 acc=make_float2(0.f,0.f);
  int p4=0;
  for(int bi=0;bi<3;++bi){
    float2 sum=make_float2(0.f,0.f);
    int qa=0;
    #pragma unroll
    for(int ai=0;ai<8;++ai){
      int q=qa;
      #pragma unroll
      for(int h4=0;h4<2;++h4){
        float4 kv=kr4[p4++];
        float2 e;
        e=E8s[q]; sum.x+=kv.x*e.x; sum.y+=kv.x*e.y; q=(q+nn)&7;
        e=E8s[q]; sum.x+=kv.y*e.x; sum.y+=kv.y*e.y; q=(q+nn)&7;
        e=E8s[q]; sum.x+=kv.z*e.x; sum.y+=kv.z*e.y; q=(q+nn)&7;
        e=E8s[q]; sum.x+=kv.w*e.x; sum.y+=kv.w*e.y; q=(q+nn)&7;
      }
      qa=(qa+dmn)&7;
    }
    float dv=D3_2[bi*286+s2];
    acc.x+=dv*sum.x; acc.y+=dv*sum.y;
  }
  const float SC2f = 0.034722222222222224f;
  acc.x*=SC2f; acc.y*=SC2f;
  K2H[((size_t)o*286+s2)*F1+i]=acc;
  float sg=((m+n)&1)?-1.f:1.f;
  K2H[((size_t)o*286+s2p)*F1+i]=make_float2(sg*acc.x,-sg*acc.y);
}

// fused2: cooperative z2 build, then wave-per-j barrier-free synthesis+integrate
__global__ __launch_bounds__(256,3) void fused2(
    const float2* __restrict__ XH2, const float2* __restrict__ K2H,
    const float* __restrict__ D2SJ, const float* __restrict__ WINT,
    const float2* __restrict__ E12, const float* __restrict__ bias2,
    float* __restrict__ FEAT){
  const int b=blockIdx.x, o=blockIdx.y, t=threadIdx.x;
  const int ln=t&63, w=t>>6;
  __shared__ __align__(16) float2 Xs[2420];
  __shared__ __align__(16) float2 Ks[2420];
  __shared__ float2 zpS[1144];
  __shared__ float2 z2S[286];
  __shared__ float  redS[256];
  float2* alias=(float2*)Xs;
  float2* TW12=alias;              // [12][17]: e^{i r (c-5) th12}, stride 17

  const int gb[4]={0,84,165,286};
  const int hb[4]={0,44,85,146};
  for(int grp=0; grp<3; ++grp){
    int row0=gb[grp], rows=gb[grp+1]-row0;
    {
      int cnt4=rows*10;
      const float4* xsrc=(const float4*)(XH2+(size_t)(b*286+row0)*F1);
      const float4* ksrc=(const float4*)(K2H+(size_t)(o*286+row0)*F1);
      float4* xd=(float4*)Xs; float4* kd=(float4*)Ks;
      for(int i=t;i<cnt4;i+=256){ xd[i]=xsrc[i]; kd[i]=ksrc[i]; }
    }
    __syncthreads();
    int nh=hb[grp+1]-hb[grp];
    for(int idx=t; idx<4*nh; idx+=256){
      int hl=idx>>2, iq=idx&3;
      int h=hb[grp]+hl;
      int l,m,n; h_decode(h,l,m,n);
      int L=2*l+1;
      int s2=B2OFFc[l]+(m+l)*L+(n+l);
      int xr0=(B2OFFc[l]-row0)+(m+l)*L;
      int kr0=(B2OFFc[l]-row0)+(n+l)*L;
      float2 acc=make_float2(0.f,0.f);
      for(int k=0;k<L;++k){
        const float2* xp=Xs+(xr0+k)*F1+iq*5;
        const float2* kp=Ks+(kr0+k)*F1+iq*5;
        #pragma unroll
        for(int i=0;i<5;++i){
          float2 xa=xp[i], kb=kp[i];
          acc.x += xa.x*kb.x + xa.y*kb.y;
          acc.y += xa.y*kb.x - xa.x*kb.y;
        }
      }
      zpS[iq*286+s2]=acc;
    }
    __syncthreads();
  }
  for(int idx=t; idx<146; idx+=256){
    int l,m,n; h_decode(idx,l,m,n);
    int L=2*l+1;
    int s2 =B2OFFc[l]+(m+l)*L+(n+l);
    int s2p=B2OFFc[l]+(l-m)*L+(l-n);
    float2 a;
    a.x=zpS[0*286+s2].x+zpS[1*286+s2].x+zpS[2*286+s2].x+zpS[3*286+s2].x;
    a.y=zpS[0*286+s2].y+zpS[1*286+s2].y+zpS[2*286+s2].y+zpS[3*286+s2].y;
    z2S[s2]=a;
    float sg=((m+n)&1)?-1.f:1.f;
    z2S[s2p]=make_float2(sg*a.x,-sg*a.y);
  }
  __syncthreads();
  for(int idx=t; idx<204; idx+=256){
    int r=idx/17, c=idx%17, n=c-5;
    int k=((r*n)%12+12)%12;
    TW12[idx]=E12[k];
  }
  __syncthreads();

  float2* G2=alias+204+w*132;
  float2* S2=G2+66;
  float*  T02=(float*)(S2+60);
  float personal=0.f;
  const float b2v=bias2[o];
  for(int jq=0;jq<3;++jq){
    const int j=jq*4+w;
    const float* Dg=D2SJ + j*286;
    // A2: 61 half items
    for(int idx=ln; idx<61; idx+=64){
      int m,n;
      if(idx<6){m=0;n=idx;} else {int q=idx-6;m=q/11+1;n=q%11-5;}
      int an=n<0?-n:n; int l=m>an?m:an; int L=2*l+1;
      int zi=B2OFFc[l]+(m+l)*L+(n+l); int m2=2*m+2;
      float2 a0=make_float2(0.f,0.f);
      for(;l<6;++l){
        float2 zv=z2S[zi]; float d=Dg[zi];
        a0.x+=zv.x*d; a0.y+=zv.y*d;
        zi+=L*L+2*L+m2; L+=2;
      }
      G2[m*11+(n+5)]=a0;
    }
    WFENCE;
    // B2: 42 items (30 S-pairs + 12 T0)
    for(int idx=ln; idx<42; idx+=64){
      if(idx<30){
        int m=idx/6+1, g=(idx%6)*2;
        const float2* Gr=&G2[m*11];
        const float2* E0=&TW12[g*17];
        const float2* E1=&TW12[(g+1)*17];
        float2 s0=make_float2(0.f,0.f), s1=s0;
        #pragma unroll
        for(int c=0;c<11;++c){
          float2 gv=Gr[c], e0=E0[c], e1=E1[c];
          s0.x+=gv.x*e0.x-gv.y*e0.y; s0.y+=gv.x*e0.y+gv.y*e0.x;
          s1.x+=gv.x*e1.x-gv.y*e1.y; s1.y+=gv.x*e1.y+gv.y*e1.x;
        }
        S2[(m-1)*12+g  ]=make_float2(2.f*s0.x,2.f*s0.y);
        S2[(m-1)*12+g+1]=make_float2(2.f*s1.x,2.f*s1.y);
      } else {
        int g=idx-30;
        const float2* Gr=&G2[5];
        const float2* Er=&TW12[g*17+5];
        float r=Gr[0].x;
        #pragma unroll
        for(int n=1;n<6;++n){ float2 gv=Gr[n], e=Er[n]; r+=2.f*(gv.x*e.x-gv.y*e.y); }
        T02[g]=r;
      }
    }
    WFENCE;
    // C2: 36 items, 4-g batch, fused relu+integrate
    {
      float wj=WINT[j];
      for(int idx=ln; idx<36; idx+=64){
        int a=idx/3, g4=(idx%3)*4;
        const float* T0p=&T02[g4];
        float v0=T0p[0]+b2v,v1=T0p[1]+b2v,v2=T0p[2]+b2v,v3=T0p[3]+b2v;
        const float2* Er=&TW12[a*17+5];
        const float2* Sc=&S2[g4];
        #pragma unroll
        for(int m=1;m<6;++m){
          float2 e=Er[m];
          const float2* Sp=Sc+(m-1)*12;
          float2 s0=Sp[0],s1=Sp[1],s2=Sp[2],s3=Sp[3];
          v0+=s0.x*e.x-s0.y*e.y; v1+=s1.x*e.x-s1.y*e.y;
          v2+=s2.x*e.x-s2.y*e.y; v3+=s3.x*e.x-s3.y*e.y;
        }
        personal += wj*((v0>0.f?v0:0.f)+(v1>0.f?v1:0.f)+(v2>0.f?v2:0.f)+(v3>0.f?v3:0.f));
      }
    }
    WFENCE;
  }
  redS[t]=personal;
  __syncthreads();
  for(int s=128;s>0;s>>=1){
    if(t<s) redS[t]+=redS[t+s];
    __syncthreads();
  }
  if(t==0) FEAT[b*F2+o]=redS[0];
}

__global__ void head_k(const float* __restrict__ FEAT, const float* __restrict__ w_out,
                       const float* __restrict__ b_lin, float* __restrict__ out){
  int idx=blockIdx.x*blockDim.x+threadIdx.x;
  if(idx>=BATCH*FOUT) return;
  int b=idx/FOUT, q=idx%FOUT;
  float acc=b_lin[q];
  for(int f=0;f<F2;++f) acc += FEAT[b*F2+f]*w_out[q*F2+f];
  out[idx]=acc;
}

extern "C" void kernel_launch(void* const* d_in, const int* in_sizes, int n_in,
                              void* d_out, int out_size, void* d_ws, size_t ws_size,
                              hipStream_t stream) {
  const float* x    =(const float*)d_in[0];
  const float* k1   =(const float*)d_in[1];
  const float* bias1=(const float*)d_in[2];
  const float* k2   =(const float*)d_in[3];
  const float* bias2=(const float*)d_in[4];
  const float* w_out=(const float*)d_in[5];
  const float* b_lin=(const float*)d_in[6];
  float* out=(float*)d_out;

  char* ws=(char*)d_ws;
  float*  A1  =(float* )(ws+0);        //  6000 f       24000
  float*  D1SJ=(float* )(ws+24000);    //  26600 f      106400 -> 130400
  float*  W3H =(float* )(ws+130400);   //  2920 f       11680  -> 142080
  float*  D2SJ=(float* )(ws+142080);   //  3432 f       13728  -> 155808
  float*  D3_2=(float* )(ws+155808);   //  858 f        3432   -> 159240 (+8 pad)
  float*  D3_1=(float* )(ws+159248);   //  300 f        1200   -> 160448
  float*  WINT=(float* )(ws+160448);   //  12 f         48     -> 160496
  float2* E60 =(float2*)(ws+160496);   //  60 c         480    -> 160976
  float2* E20 =(float2*)(ws+160976);   //  20 c         160    -> 161136
  float2* E12 =(float2*)(ws+161136);   //  12 c         96     -> 161232 (+16 pad)
  float2* XHAT=(float2*)(ws+161248);   //  [b][100] c   102400 -> 263648
  float2* K1H =(float2*)(ws+263648);   //  [o][100] c   16000  -> 279648
  float2* XH2 =(float2*)(ws+279648);   //  [b][286][20] 5857280-> 6136928
  float2* K2H =(float2*)(ws+6136928);  //  [o][286][20] 1830400-> 7967328
  float*  FEAT=(float* )(ws+7967328);  //  128*40 f     20480  -> 7987808

  (void)in_sizes; (void)n_in; (void)out_size; (void)ws_size;

  gen_all<<<161,256,0,stream>>>(A1,D1SJ,W3H,D2SJ,D3_2,D3_1,WINT,E60,E20,E12);
  front_k<<<136,256,0,stream>>>(x,k1,E60,A1,D3_1,XHAT,K1H);
  dim3 g1(BATCH,F1);
  fused1<<<g1,256,0,stream>>>(XHAT,K1H,D1SJ,W3H,E20,bias1,XH2);
  k2h_k<<<(NH2*F1*F2+255)/256,256,0,stream>>>(k2,D3_2,K2H);
  dim3 g2(BATCH,F2);
  fused2<<<g2,256,0,stream>>>(XH2,K2H,D2SJ,WINT,E12,bias2,FEAT);
  head_k<<<(BATCH*FOUT+255)/256,256,0,stream>>>(FEAT,w_out,b_lin,out);
}